// Round 4
// baseline (685.660 us; speedup 1.0000x reference)
//
#include <hip/hip_runtime.h>
#include <hip/hip_bf16.h>
#include <math.h>

#define BN    32
#define NTOK  785
#define GH    28
#define GW    28
#define DIM   768
#define QKVD  2304
#define NH    8
#define HD    96
#define MROWS (BN*NTOK)   // 25120
#define NS    4           // attn token-split
#define NPC   197         // ceil(785/4)

typedef __hip_bfloat16 bf16;
typedef unsigned short ushort_t;
typedef short s16x8 __attribute__((ext_vector_type(8)));   // 8 bf16 = 4 VGPRs
typedef float f32x4 __attribute__((ext_vector_type(4)));   // MFMA acc

// ---------------------------------------------------------------------------
// helpers
// ---------------------------------------------------------------------------
__device__ __forceinline__ void gl2lds16(const void* g, void* l) {
    // 16B per lane, LDS dest = wave-uniform base + lane*16
    __builtin_amdgcn_global_load_lds(
        (__attribute__((address_space(1))) void*)const_cast<void*>(g),
        (__attribute__((address_space(3))) void*)l, 16, 0, 0);
}

__device__ __forceinline__ ushort_t f2bf(float f) {
    bf16 h = __float2bfloat16(f);
    return *(ushort_t*)&h;
}

// ---------------------------------------------------------------------------
// K-1: fp32 -> bf16 convert (x -> xb). 8 elems/thread, vectorized.
// ---------------------------------------------------------------------------
__global__ __launch_bounds__(256)
void f32_to_bf16_kernel(const float* __restrict__ in, ushort_t* __restrict__ out,
                        int n8) {
    int i = blockIdx.x * 256 + threadIdx.x;
    if (i >= n8) return;
    const float4* p = (const float4*)(in + (size_t)i * 8);
    float4 a = p[0], b = p[1];
    union { s16x8 v; __hip_bfloat162 h[4]; } r;
    r.h[0] = __float22bfloat162_rn(make_float2(a.x, a.y));
    r.h[1] = __float22bfloat162_rn(make_float2(a.z, a.w));
    r.h[2] = __float22bfloat162_rn(make_float2(b.x, b.y));
    r.h[3] = __float22bfloat162_rn(make_float2(b.z, b.w));
    *(s16x8*)(out + (size_t)i * 8) = r.v;
}

// ---------------------------------------------------------------------------
// K0: transpose-convert W[R][C] fp32 -> Wt[C][R] bf16
// ---------------------------------------------------------------------------
__global__ __launch_bounds__(256)
void transpose_bf16_kernel(const float* __restrict__ W, ushort_t* __restrict__ Wt,
                           int R, int C) {
    __shared__ float tile[32][33];
    int c0 = blockIdx.x * 32, r0 = blockIdx.y * 32;
    int tx = threadIdx.x, ty = threadIdx.y;   // 32 x 8
    #pragma unroll
    for (int i = 0; i < 4; ++i)
        tile[ty + i * 8][tx] = W[(size_t)(r0 + ty + i * 8) * C + c0 + tx];
    __syncthreads();
    #pragma unroll
    for (int i = 0; i < 4; ++i)
        Wt[(size_t)(c0 + ty + i * 8) * R + r0 + tx] = f2bf(tile[tx][ty + i * 8]);
}

// ---------------------------------------------------------------------------
// K1: qkv GEMM, 256x256 tile / BK=64 / 8 waves (2Mx4N), depth-2 pipeline with
// counted vmcnt across RAW barriers (T3+T4), setprio around MFMA (T5).
// LDS 128 KB: A[2][256][64] + B[2][256][64] bf16, slot-swizzled:
//   phys_slot = logical_slot ^ (row & 7)   (slot = 16B unit of the 128B row)
// Staging keeps LDS linear (global_load_lds, lane i -> row i>>3, slot i&7 of an
// 8-row group) and pre-swizzles the GLOBAL source: src_slot = (lane&7)^(lane>>3).
// ds_read applies the same involution: slot' = (kh*4+q4) ^ (l15&7) -> 2-way banks.
// ---------------------------------------------------------------------------
__global__ __launch_bounds__(512, 2)
void gemm_qkv_256(const ushort_t* __restrict__ A, const ushort_t* __restrict__ Bt,
                  const float* __restrict__ bias,
                  ushort_t* __restrict__ q, ushort_t* __restrict__ kk_,
                  ushort_t* __restrict__ v) {
    __shared__ ushort_t Asm[2][256 * 64];   // 64 KB
    __shared__ ushort_t Bsm[2][256 * 64];   // 64 KB
    const int tid  = threadIdx.x;
    const int wave = tid >> 6;     // 0..7
    const int lane = tid & 63;

    // bijective XCD swizzle (m204 form): nwg = 9*99 = 891
    const int nwg  = gridDim.x * gridDim.y;
    const int orig = blockIdx.y * gridDim.x + blockIdx.x;
    const int qd = nwg >> 3, r8 = nwg & 7;
    const int xcd = orig & 7, idx = orig >> 3;
    const int swb = (xcd < r8 ? xcd * (qd + 1) : r8 * (qd + 1) + (xcd - r8) * qd) + idx;
    const int bx = swb % gridDim.x;
    const int by = swb / gridDim.x;
    const int row0 = by * 256, col0 = bx * 256;

    const int wm = wave >> 2, wn = wave & 3;
    const int q4 = lane >> 4, l15 = lane & 15;
    const int sg = ((lane & 7) ^ (lane >> 3)) * 8;   // staging global slot (elems)

    f32x4 acc[8][4];
    #pragma unroll
    for (int i = 0; i < 8; ++i)
        #pragma unroll
        for (int j = 0; j < 4; ++j) acc[i][j] = (f32x4){0.f, 0.f, 0.f, 0.f};

#define STAGE_Q(buf, kt)                                                       \
    {                                                                          \
        _Pragma("unroll")                                                      \
        for (int rr = 0; rr < 4; ++rr) {                                       \
            int lrow = wave * 32 + rr * 8;                                     \
            int garow = min(row0 + lrow + (lane >> 3), MROWS - 1);             \
            gl2lds16(A + (size_t)garow * DIM + (kt) + sg,                      \
                     &Asm[buf][lrow * 64]);                                    \
            int gbrow = col0 + lrow + (lane >> 3);                             \
            gl2lds16(Bt + (size_t)gbrow * DIM + (kt) + sg,                     \
                     &Bsm[buf][lrow * 64]);                                    \
        }                                                                      \
    }

    STAGE_Q(0, 0);
    STAGE_Q(1, 64);
    asm volatile("s_waitcnt vmcnt(8)" ::: "memory");
    __builtin_amdgcn_sched_barrier(0);
    __builtin_amdgcn_s_barrier();
    __builtin_amdgcn_sched_barrier(0);

    for (int t = 0; t < 12; ++t) {
        const int cur = t & 1;
        const ushort_t* Ab = Asm[cur];
        const ushort_t* Bb = Bsm[cur];
        #pragma unroll
        for (int kh = 0; kh < 2; ++kh) {
            const int sl = ((kh * 4 + q4) ^ (l15 & 7)) * 8;
            s16x8 bfr[4], af[8];
            #pragma unroll
            for (int ni = 0; ni < 4; ++ni)
                bfr[ni] = *(const s16x8*)&Bb[(wn * 64 + ni * 16 + l15) * 64 + sl];
            #pragma unroll
            for (int mi = 0; mi < 8; ++mi)
                af[mi] = *(const s16x8*)&Ab[(wm * 128 + mi * 16 + l15) * 64 + sl];
            __builtin_amdgcn_s_setprio(1);
            #pragma unroll
            for (int mi = 0; mi < 8; ++mi)
                #pragma unroll
                for (int ni = 0; ni < 4; ++ni)
                    acc[mi][ni] = __builtin_amdgcn_mfma_f32_16x16x32_bf16(
                        af[mi], bfr[ni], acc[mi][ni], 0, 0, 0);
            __builtin_amdgcn_s_setprio(0);
        }
        __builtin_amdgcn_sched_barrier(0);
        __builtin_amdgcn_s_barrier();          // all waves done reading buf[cur]
        __builtin_amdgcn_sched_barrier(0);
        if (t + 2 < 12) {
            STAGE_Q(cur, (t + 2) * 64);
            asm volatile("s_waitcnt vmcnt(8)" ::: "memory");  // tile t+1 landed
        } else {
            asm volatile("s_waitcnt vmcnt(0)" ::: "memory");
        }
        __builtin_amdgcn_sched_barrier(0);
        __builtin_amdgcn_s_barrier();          // tile t+1 visible to all waves
        __builtin_amdgcn_sched_barrier(0);
    }
#undef STAGE_Q

    const int colbase = col0 + wn * 64;
    const int seg = colbase / DIM;             // uniform per block (256 | 768)
    const int csub = colbase - seg * DIM;
    ushort_t* outp = (seg == 0) ? q : (seg == 1) ? kk_ : v;
    #pragma unroll
    for (int mi = 0; mi < 8; ++mi) {
        #pragma unroll
        for (int ni = 0; ni < 4; ++ni) {
            int gcol = colbase + ni * 16 + l15;
            int col  = csub + ni * 16 + l15;
            float bb = bias[gcol];
            #pragma unroll
            for (int j = 0; j < 4; ++j) {
                int row = row0 + wm * 128 + mi * 16 + q4 * 4 + j;
                if (row < MROWS)
                    outp[(size_t)row * DIM + col] = f2bf(acc[mi][ni][j] + bb);
            }
        }
    }
}

// ---------------------------------------------------------------------------
// K6: out GEMM via MFMA. A = o bf16, Bt = W_out^T bf16, C fp32.
// 128x128 tile, swizzled LDS (r0 structure).
// ---------------------------------------------------------------------------
__global__ __launch_bounds__(256)
void gemm_out_mfma(const ushort_t* __restrict__ A, const ushort_t* __restrict__ Bt,
                   const float* __restrict__ bias, float* __restrict__ C) {
    const int M = MROWS, N = DIM, K = DIM;
    __shared__ ushort_t Asm[128 * 32];
    __shared__ ushort_t Bsm[128 * 32];
    const int tid  = threadIdx.x;
    const int wave = tid >> 6;
    const int lane = tid & 63;
    const int row0 = blockIdx.y * 128;
    const int col0 = blockIdx.x * 128;
    const int wm = wave >> 1, wn = wave & 1;
    const int q4 = lane >> 4, l15 = lane & 15;
    const int slotg = (lane & 3) ^ ((lane >> 3) & 3);
    const int swz   = (l15 >> 1) & 3;

    f32x4 acc[4][4];
    #pragma unroll
    for (int i = 0; i < 4; ++i)
        #pragma unroll
        for (int j = 0; j < 4; ++j) acc[i][j] = (f32x4){0.f, 0.f, 0.f, 0.f};

    for (int kt = 0; kt < K; kt += 32) {
        #pragma unroll
        for (int r = 0; r < 2; ++r) {
            int seg = r * 4 + wave;
            int rit = seg * 16 + (lane >> 2);
            int grow = min(row0 + rit, M - 1);
            const ushort_t* gp = A + (size_t)grow * K + kt + slotg * 8;
            gl2lds16(gp, &Asm[seg * 512]);
        }
        #pragma unroll
        for (int r = 0; r < 2; ++r) {
            int seg = r * 4 + wave;
            int nit = seg * 16 + (lane >> 2);
            const ushort_t* gp = Bt + (size_t)(col0 + nit) * K + kt + slotg * 8;
            gl2lds16(gp, &Bsm[seg * 512]);
        }
        __syncthreads();
        s16x8 af[4], bfr[4];
        #pragma unroll
        for (int mi = 0; mi < 4; ++mi)
            af[mi] = *(const s16x8*)&Asm[(wm * 64 + mi * 16 + l15) * 32
                                         + ((q4 ^ swz) * 8)];
        #pragma unroll
        for (int ni = 0; ni < 4; ++ni)
            bfr[ni] = *(const s16x8*)&Bsm[(wn * 64 + ni * 16 + l15) * 32
                                          + ((q4 ^ swz) * 8)];
        #pragma unroll
        for (int mi = 0; mi < 4; ++mi)
            #pragma unroll
            for (int ni = 0; ni < 4; ++ni)
                acc[mi][ni] = __builtin_amdgcn_mfma_f32_16x16x32_bf16(
                    af[mi], bfr[ni], acc[mi][ni], 0, 0, 0);
        __syncthreads();
    }
    #pragma unroll
    for (int mi = 0; mi < 4; ++mi) {
        #pragma unroll
        for (int ni = 0; ni < 4; ++ni) {
            int col = col0 + wn * 64 + ni * 16 + l15;
            float bb = bias[col];
            #pragma unroll
            for (int j = 0; j < 4; ++j) {
                int row = row0 + wm * 64 + mi * 16 + q4 * 4 + j;
                if (row < M)
                    C[(size_t)row * N + col] = acc[mi][ni][j] + bb;
            }
        }
    }
}

// ---------------------------------------------------------------------------
// K2: per-(b,c) softmax stats over 785 tokens of k
// ---------------------------------------------------------------------------
__global__ __launch_bounds__(256)
void softmax_stats_kernel(const bf16* __restrict__ k,
                          float* __restrict__ stat_m, float* __restrict__ stat_is) {
    int b = blockIdx.y;
    int c = blockIdx.x * 64 + threadIdx.x;
    int ty = threadIdx.y;
    const bf16* base = k + (size_t)b * NTOK * DIM + c;
    float m = -1e30f, s = 0.f;
    for (int n = ty; n < NTOK; n += 4) {
        float kv = __bfloat162float(base[(size_t)n * DIM]);
        float nm = fmaxf(m, kv);
        s = s * __expf(m - nm) + __expf(kv - nm);
        m = nm;
    }
    __shared__ float sm[4][64], ss[4][64];
    sm[ty][threadIdx.x] = m; ss[ty][threadIdx.x] = s;
    __syncthreads();
    if (ty == 0) {
        float M = sm[0][threadIdx.x];
        #pragma unroll
        for (int i = 1; i < 4; ++i) M = fmaxf(M, sm[i][threadIdx.x]);
        float S = 0.f;
        #pragma unroll
        for (int i = 0; i < 4; ++i) S += ss[i][threadIdx.x] * __expf(sm[i][threadIdx.x] - M);
        stat_m[b * DIM + c] = M;
        stat_is[b * DIM + c] = 1.f / S;
    }
}

// ---------------------------------------------------------------------------
// K3: attn_part[ns][b,h,d,e] = sum_{n in chunk ns} exp(k[n,d]-m_d) * v[n,e]
// ---------------------------------------------------------------------------
__global__ __launch_bounds__(256)
void attn_kernel(const bf16* __restrict__ k, const bf16* __restrict__ v,
                 const float* __restrict__ stat_m,
                 float* __restrict__ attn_part) {
    int h = blockIdx.x, b = blockIdx.y, ns = blockIdx.z;
    int tx = threadIdx.x, ty = threadIdx.y;
    int t = ty * 16 + tx;
    __shared__ float ek[32][98], vv[32][98];
    __shared__ float smM[96];
    if (t < 96) smM[t] = stat_m[b * DIM + h * HD + t];
    __syncthreads();
    float acc[6][6] = {};
    const bf16* kbase = k + (size_t)b * NTOK * DIM + h * HD;
    const bf16* vbase = v + (size_t)b * NTOK * DIM + h * HD;
    const int nlo = ns * NPC;
    const int nhi = min(NTOK, nlo + NPC);
    const int tl = t >> 3;          // token slot 0..31
    const int cg = (t & 7) * 12;    // channel 0,12,..,84
    for (int n0 = nlo; n0 < nhi; n0 += 32) {
        int n = n0 + tl;
        float2 tk[6], tv[6];
        if (n < nhi) {
            #pragma unroll
            for (int j = 0; j < 6; ++j) {
                float2 kf = __bfloat1622float2(
                    *(const __hip_bfloat162*)&kbase[(size_t)n * DIM + cg + 2 * j]);
                float2 vf = __bfloat1622float2(
                    *(const __hip_bfloat162*)&vbase[(size_t)n * DIM + cg + 2 * j]);
                tk[j].x = __expf(kf.x - smM[cg + 2 * j]);
                tk[j].y = __expf(kf.y - smM[cg + 2 * j + 1]);
                tv[j] = vf;
            }
        } else {
            #pragma unroll
            for (int j = 0; j < 6; ++j) {
                tk[j] = make_float2(0.f, 0.f);
                tv[j] = make_float2(0.f, 0.f);
            }
        }
        #pragma unroll
        for (int j = 0; j < 6; ++j) {
            *(float2*)&ek[tl][cg + 2 * j] = tk[j];
            *(float2*)&vv[tl][cg + 2 * j] = tv[j];
        }
        __syncthreads();
        #pragma unroll
        for (int nl = 0; nl < 32; ++nl) {
            float2 ka01 = *(const float2*)&ek[nl][tx * 6];
            float2 ka23 = *(const float2*)&ek[nl][tx * 6 + 2];
            float2 ka45 = *(const float2*)&ek[nl][tx * 6 + 4];
            float2 vb01 = *(const float2*)&vv[nl][ty * 6];
            float2 vb23 = *(const float2*)&vv[nl][ty * 6 + 2];
            float2 vb45 = *(const float2*)&vv[nl][ty * 6 + 4];
            float ka[6] = {ka01.x, ka01.y, ka23.x, ka23.y, ka45.x, ka45.y};
            float vb[6] = {vb01.x, vb01.y, vb23.x, vb23.y, vb45.x, vb45.y};
            #pragma unroll
            for (int i = 0; i < 6; ++i)
                #pragma unroll
                for (int j = 0; j < 6; ++j)
                    acc[i][j] += ka[i] * vb[j];
        }
        __syncthreads();
    }
    float* abase = attn_part + (size_t)ns * BN * NH * HD * HD
                 + ((size_t)(b * NH + h)) * HD * HD;
    #pragma unroll
    for (int i = 0; i < 6; ++i)
        #pragma unroll
        for (int j = 0; j < 6; ++j)
            abase[(size_t)(tx * 6 + i) * HD + ty * 6 + j] = acc[i][j];
}

// ---------------------------------------------------------------------------
// K3b: attn[b,h,d,e] = stat_is[b,h*96+d] * sum_s attn_part[s][b,h,d,e]
// ---------------------------------------------------------------------------
__global__ __launch_bounds__(256)
void attn_reduce_kernel(const float* __restrict__ part,
                        const float* __restrict__ stat_is,
                        float* __restrict__ attn) {
    const int TOT4 = BN * NH * HD * HD / 4;   // 589824
    int i = blockIdx.x * 256 + threadIdx.x;
    if (i >= TOT4) return;
    size_t base = (size_t)i * 4;
    int bh = (int)(base / (HD * HD));
    int d  = (int)((base / HD) % HD);
    float is = stat_is[(bh >> 3) * DIM + (bh & 7) * HD + d];
    const size_t PSZ = (size_t)BN * NH * HD * HD;
    float4 s = *(const float4*)&part[base];
    float4 p1 = *(const float4*)&part[PSZ + base];
    float4 p2 = *(const float4*)&part[2 * PSZ + base];
    float4 p3 = *(const float4*)&part[3 * PSZ + base];
    s.x = (s.x + p1.x + p2.x + p3.x) * is;
    s.y = (s.y + p1.y + p2.y + p3.y) * is;
    s.z = (s.z + p1.z + p2.z + p3.z) * is;
    s.w = (s.w + p1.w + p2.w + p3.w) * is;
    *(float4*)&attn[base] = s;
}

// ---------------------------------------------------------------------------
// K4: CRPE depthwise conv, restructured for occupancy + branch-free taps.
// ---------------------------------------------------------------------------
#define CRS 1104   // conv tile row stride in bf16 elems (34*32 + 16 pad)

template<int KS>
__device__ __forceinline__ void crpe_conv32(const ushort_t* __restrict__ vimg,
                                            const float* __restrict__ wsm,
                                            float b0, float b1,
                                            ushort_t* __restrict__ ob,
                                            int p, int yl, int y) {
    constexpr int R = KS / 2;
    const float* wA = wsm + (2 * p) * KS * KS;
    const float* wB = wA + KS * KS;
    #pragma unroll
    for (int xo = 0; xo < 28; xo += 7) {
        float a0[7], a1[7];
        #pragma unroll
        for (int u = 0; u < 7; ++u) { a0[u] = b0; a1[u] = b1; }
        #pragma unroll
        for (int ky = 0; ky < KS; ++ky) {
            const ushort_t* rp = vimg + (yl + ky - R + 3) * CRS
                                      + (xo - R + 3) * 32 + 2 * p;
            float2 seg[6 + KS];
            #pragma unroll
            for (int i = 0; i < 6 + KS; ++i)
                seg[i] = __bfloat1622float2(*(const __hip_bfloat162*)(rp + i * 32));
            #pragma unroll
            for (int kx = 0; kx < KS; ++kx) {
                float wa = wA[ky * KS + kx];
                float wb = wB[ky * KS + kx];
                #pragma unroll
                for (int u = 0; u < 7; ++u) {
                    a0[u] = fmaf(wa, seg[u + kx].x, a0[u]);
                    a1[u] = fmaf(wb, seg[u + kx].y, a1[u]);
                }
            }
        }
        #pragma unroll
        for (int u = 0; u < 7; ++u)
            *(__hip_bfloat162*)&ob[(size_t)(1 + y * GW + xo + u) * DIM + 2 * p] =
                __float22bfloat162_rn(make_float2(a0[u], a1[u]));
    }
}

__global__ __launch_bounds__(256)
void crpe_lds_kernel(const ushort_t* __restrict__ v,
                     const float* __restrict__ w3, const float* __restrict__ b3,
                     const float* __restrict__ w5, const float* __restrict__ b5,
                     const float* __restrict__ w7, const float* __restrict__ b7,
                     ushort_t* __restrict__ o) {
    __shared__ ushort_t vimg[20 * CRS];   // 44,160 B
    __shared__ float    wsm[32 * 49];     //  6,272 B
    const int cg  = blockIdx.x;    // 0..23, 32-channel group
    const int hf  = blockIdx.y;    // 0..1 image half (rows 0..13 / 14..27)
    const int b   = blockIdx.z;
    const int tid = threadIdx.x;
    const int c0  = cg * 32;

    const float* wsrc; const float* bsrc; int ks;
    if (c0 < 192)      { wsrc = w3 + c0 * 9;          bsrc = b3 + c0;         ks = 3; }
    else if (c0 < 480) { wsrc = w5 + (c0 - 192) * 25; bsrc = b5 + (c0 - 192); ks = 5; }
    else               { wsrc = w7 + (c0 - 480) * 49; bsrc = b7 + (c0 - 480); ks = 7; }
    const int ksq = ks * ks;

    const int zr0 = hf ? 17 : 0;
    for (int idx = tid; idx < 3 * 138; idx += 256) {
        int rr = idx / 138, cc = idx - rr * 138;
        *(s16x8*)&vimg[(zr0 + rr) * CRS + cc * 8] = (s16x8){0,0,0,0,0,0,0,0};
    }
    for (int idx = tid; idx < 17 * 24; idx += 256) {
        int vr = idx / 24, cc = idx - vr * 24;
        int ly = hf ? vr : vr + 3;
        int ch = (cc < 12) ? cc : (112 + cc);
        *(s16x8*)&vimg[ly * CRS + ch * 8] = (s16x8){0,0,0,0,0,0,0,0};
    }
    for (int idx = tid; idx < 32 * ksq; idx += 256)
        wsm[idx] = wsrc[idx];
    const ushort_t* vb = v + (size_t)b * NTOK * DIM + c0;
    const int gy0 = hf ? 11 : 0;
    for (int idx = tid; idx < 17 * 28 * 4; idx += 256) {
        int vr = idx / 112, rem = idx - vr * 112;
        int px = rem >> 2, c8 = rem & 3;
        int gy = gy0 + vr;
        int ly = hf ? vr : vr + 3;
        *(s16x8*)&vimg[ly * CRS + (px + 3) * 32 + c8 * 8] =
            *(const s16x8*)(vb + (size_t)(1 + gy * GW + px) * DIM + c8 * 8);
    }
    ushort_t* ob = o + (size_t)b * NTOK * DIM + c0;
    if (hf == 0 && tid < 32) ob[tid] = 0;   // CLS row: rp = 0
    __syncthreads();

    const int p  = tid & 15;       // channel pair 0..15
    const int yl = tid >> 4;       // row within half 0..15
    if (yl >= 14) return;
    const int y = hf * 14 + yl;    // global row
    float bb0 = bsrc[2 * p], bb1 = bsrc[2 * p + 1];
    if (ks == 3)      crpe_conv32<3>(vimg, wsm, bb0, bb1, ob, p, yl, y);
    else if (ks == 5) crpe_conv32<5>(vimg, wsm, bb0, bb1, ob, p, yl, y);
    else              crpe_conv32<7>(vimg, wsm, bb0, bb1, ob, p, yl, y);
}

// ---------------------------------------------------------------------------
// K5: o[b,n,h*96+e] = scale * sum_d q[n,d] attn[d,e] + q[n,e] * rp (in-place)
// ---------------------------------------------------------------------------
__global__ __launch_bounds__(256)
void combine_kernel(const bf16* __restrict__ q, const float* __restrict__ attn,
                    bf16* __restrict__ o) {
    int h = blockIdx.x;
    int n0 = blockIdx.y * 64;
    int b = blockIdx.z;
    int tx = threadIdx.x, ty = threadIdx.y;
    int t = ty * 16 + tx;
    __shared__ float as[96][96];
    __shared__ float qs[64][97];
    const float* abase = attn + ((size_t)(b * NH + h)) * HD * HD;
    #pragma unroll
    for (int i = 0; i < 36; ++i) {
        int idx = t + i * 256;
        as[idx / 96][idx % 96] = abase[idx];
    }
    const bf16* qbase = q + (size_t)b * NTOK * DIM + h * HD;
    #pragma unroll
    for (int i = 0; i < 24; ++i) {
        int idx = t + i * 256;
        int rr = idx / 96, cc = idx % 96;
        int n = n0 + rr;
        qs[rr][cc] = (n < NTOK) ? __bfloat162float(qbase[(size_t)n * DIM + cc]) : 0.f;
    }
    __syncthreads();
    float acc[4][6] = {};
    for (int d = 0; d < 96; ++d) {
        float qa[4], ab[6];
        #pragma unroll
        for (int i = 0; i < 4; ++i) qa[i] = qs[ty * 4 + i][d];
        #pragma unroll
        for (int j = 0; j < 6; ++j) ab[j] = as[d][tx * 6 + j];
        #pragma unroll
        for (int i = 0; i < 4; ++i)
            #pragma unroll
            for (int j = 0; j < 6; ++j)
                acc[i][j] += qa[i] * ab[j];
    }
    const float scale = 0.10206207261596575f;  // 96^-0.5
    bf16* obase = o + (size_t)b * NTOK * DIM + h * HD;
    #pragma unroll
    for (int i = 0; i < 4; ++i) {
        int n = n0 + ty * 4 + i;
        if (n >= NTOK) continue;
        #pragma unroll
        for (int j = 0; j < 6; ++j) {
            int e = tx * 6 + j;
            size_t oa = (size_t)n * DIM + e;
            float rp = __bfloat162float(obase[oa]);
            float qv = qs[ty * 4 + i][e];
            obase[oa] = __float2bfloat16(scale * acc[i][j] + qv * rp);
        }
    }
}

// ---------------------------------------------------------------------------
extern "C" void kernel_launch(void* const* d_in, const int* in_sizes, int n_in,
                              void* d_out, int out_size, void* d_ws, size_t ws_size,
                              hipStream_t stream) {
    const float* x     = (const float*)d_in[0];
    const float* W_qkv = (const float*)d_in[1];
    const float* b_qkv = (const float*)d_in[2];
    const float* W_out = (const float*)d_in[3];
    const float* b_out = (const float*)d_in[4];
    const float* w3    = (const float*)d_in[5];
    const float* cb3   = (const float*)d_in[6];
    const float* w5    = (const float*)d_in[7];
    const float* cb5   = (const float*)d_in[8];
    const float* w7    = (const float*)d_in[9];
    const float* cb7   = (const float*)d_in[10];
    float* out = (float*)d_out;

    ushort_t* q = (ushort_t*)d_ws;
    ushort_t* k = q + (size_t)MROWS * DIM;
    ushort_t* v = k + (size_t)MROWS * DIM;
    float* attn    = (float*)(v + (size_t)MROWS * DIM);
    float* stat_m  = attn + (size_t)BN * NH * HD * HD;
    float* stat_is = stat_m + (size_t)BN * DIM;
    ushort_t* Wqkvt = (ushort_t*)(stat_is + (size_t)BN * DIM);
    ushort_t* Wot   = Wqkvt + (size_t)QKVD * DIM;
    ushort_t* o = k;   // alias: k dead after attn_kernel

    // d_out scratch layout: xb (bf16 x, 38.58 MB) then attn_part (37.75 MB).
    // Both dead before gemm_out_mfma writes d_out (77.17 MB total).
    ushort_t* xb = (ushort_t*)d_out;
    float* attn_part = (float*)d_out + (size_t)MROWS * DIM / 2;

    transpose_bf16_kernel<<<dim3(QKVD / 32, DIM / 32), dim3(32, 8), 0, stream>>>(
        W_qkv, Wqkvt, DIM, QKVD);
    transpose_bf16_kernel<<<dim3(DIM / 32, DIM / 32), dim3(32, 8), 0, stream>>>(
        W_out, Wot, DIM, DIM);
    {
        int n8 = MROWS * DIM / 8;
        f32_to_bf16_kernel<<<dim3((n8 + 255) / 256), 256, 0, stream>>>(x, xb, n8);
    }
    gemm_qkv_256<<<dim3(QKVD / 256, (MROWS + 255) / 256), 512, 0, stream>>>(
        xb, Wqkvt, b_qkv, q, k, v);
    softmax_stats_kernel<<<dim3(12, BN), dim3(64, 4), 0, stream>>>(
        (const bf16*)k, stat_m, stat_is);
    attn_kernel<<<dim3(NH, BN, NS), dim3(16, 16), 0, stream>>>(
        (const bf16*)k, (const bf16*)v, stat_m, attn_part);
    {
        int tot4 = BN * NH * HD * HD / 4;
        attn_reduce_kernel<<<dim3((tot4 + 255) / 256), 256, 0, stream>>>(
            attn_part, stat_is, attn);
    }
    crpe_lds_kernel<<<dim3(24, 2, BN), 256, 0, stream>>>(
        v, w3, cb3, w5, cb5, w7, cb7, o);
    combine_kernel<<<dim3(NH, 13, BN), dim3(16, 16), 0, stream>>>(
        (const bf16*)q, attn, (bf16*)o);
    gemm_out_mfma<<<dim3(DIM / 128, (MROWS + 127) / 128), 256, 0, stream>>>(
        o, Wot, b_out, out);
}

// Round 5
// 682.273 us; speedup vs baseline: 1.0050x; 1.0050x over previous
//
#include <hip/hip_runtime.h>
#include <hip/hip_bf16.h>
#include <math.h>

#define BN    32
#define NTOK  785
#define GH    28
#define GW    28
#define DIM   768
#define QKVD  2304
#define NH    8
#define HD    96
#define MROWS (BN*NTOK)   // 25120
#define NS    4           // attn token-split
#define NPC   197         // ceil(785/4)

typedef __hip_bfloat16 bf16;
typedef unsigned short ushort_t;
typedef short s16x8 __attribute__((ext_vector_type(8)));   // 8 bf16 = 4 VGPRs
typedef float f32x4 __attribute__((ext_vector_type(4)));   // MFMA acc

// ---------------------------------------------------------------------------
// helpers
// ---------------------------------------------------------------------------
__device__ __forceinline__ void gl2lds16(const void* g, void* l) {
    // 16B per lane, LDS dest = wave-uniform base + lane*16
    __builtin_amdgcn_global_load_lds(
        (__attribute__((address_space(1))) void*)const_cast<void*>(g),
        (__attribute__((address_space(3))) void*)l, 16, 0, 0);
}

__device__ __forceinline__ ushort_t f2bf(float f) {
    bf16 h = __float2bfloat16(f);
    return *(ushort_t*)&h;
}

// ---------------------------------------------------------------------------
// K-1: fp32 -> bf16 convert (x -> xb). 8 elems/thread, vectorized.
// ---------------------------------------------------------------------------
__global__ __launch_bounds__(256)
void f32_to_bf16_kernel(const float* __restrict__ in, ushort_t* __restrict__ out,
                        int n8) {
    int i = blockIdx.x * 256 + threadIdx.x;
    if (i >= n8) return;
    const float4* p = (const float4*)(in + (size_t)i * 8);
    float4 a = p[0], b = p[1];
    union { s16x8 v; __hip_bfloat162 h[4]; } r;
    r.h[0] = __float22bfloat162_rn(make_float2(a.x, a.y));
    r.h[1] = __float22bfloat162_rn(make_float2(a.z, a.w));
    r.h[2] = __float22bfloat162_rn(make_float2(b.x, b.y));
    r.h[3] = __float22bfloat162_rn(make_float2(b.z, b.w));
    *(s16x8*)(out + (size_t)i * 8) = r.v;
}

// ---------------------------------------------------------------------------
// K0: transpose-convert W[R][C] fp32 -> Wt[C][R] bf16
// ---------------------------------------------------------------------------
__global__ __launch_bounds__(256)
void transpose_bf16_kernel(const float* __restrict__ W, ushort_t* __restrict__ Wt,
                           int R, int C) {
    __shared__ float tile[32][33];
    int c0 = blockIdx.x * 32, r0 = blockIdx.y * 32;
    int tx = threadIdx.x, ty = threadIdx.y;   // 32 x 8
    #pragma unroll
    for (int i = 0; i < 4; ++i)
        tile[ty + i * 8][tx] = W[(size_t)(r0 + ty + i * 8) * C + c0 + tx];
    __syncthreads();
    #pragma unroll
    for (int i = 0; i < 4; ++i)
        Wt[(size_t)(c0 + ty + i * 8) * R + r0 + tx] = f2bf(tile[tx][ty + i * 8]);
}

// ---------------------------------------------------------------------------
// K1: qkv GEMM, 256x256 / BK=64 / 8 waves, TRUE 8-phase schedule (T3+T4+T5).
// Per K-tile: 4 phases, each = {ds_read quadrant frags || stage one 128-row
// half-region of a future tile -> barrier -> lgkmcnt(0) -> 16 MFMA -> barrier}.
// Staging runs 3 half-regions ahead; ONE vmcnt(6) per K-tile (phase 3).
// Regions: A-R0 = rows {[0,64)u[128,192)} (read ph0), A-R1 = +64 (read ph2),
//          B-S0 = rows {wn*64+[0,32)} (read ph0), B-S1 = +32 (read ph1).
// Stage schedule during tile T (cur=T&1):
//   ph0: B-S1(t+1)->buf[cur^1]   (region free since T-1.ph1)
//   ph1: A-R0(t+2)->buf[cur]     (free after this tile's ph0)
//   ph2: B-S0(t+2)->buf[cur]     (free after ph0)
//   ph3: A-R1(t+2)->buf[cur]     (free after ph2); vmcnt(6)
// Visibility: tile T's 4 regions staged <= T-1.ph0; T-1's ph3 vmcnt(6)
// drains exactly through T-1.ph0 (14 outstanding -> 6), then barrier.
// Slot swizzle (both-sides, rule #21): store slot_phys = slot ^ (row&7) via
// pre-swizzled global src sg = ((lane&7)^((lane>>3)&7))*8; read slot' =
// (kh*4+q4)^(l15&7)  -> 2-way banks (free).
// ---------------------------------------------------------------------------
#define BARRIER_PRE()  do { __builtin_amdgcn_sched_barrier(0);                 \
    __builtin_amdgcn_s_barrier();                                              \
    asm volatile("s_waitcnt lgkmcnt(0)" ::: "memory");                         \
    __builtin_amdgcn_sched_barrier(0); } while (0)
#define BARRIER_POST() do { __builtin_amdgcn_sched_barrier(0);                 \
    __builtin_amdgcn_s_barrier();                                              \
    __builtin_amdgcn_sched_barrier(0); } while (0)

__global__ __launch_bounds__(512, 2)
void gemm_qkv_256(const ushort_t* __restrict__ A, const ushort_t* __restrict__ Bt,
                  const float* __restrict__ bias,
                  ushort_t* __restrict__ q, ushort_t* __restrict__ kk_,
                  ushort_t* __restrict__ v) {
    __shared__ ushort_t Asm[2][256 * 64];   // 64 KB
    __shared__ ushort_t Bsm[2][256 * 64];   // 64 KB
    const int tid  = threadIdx.x;
    const int wave = tid >> 6;     // 0..7
    const int lane = tid & 63;

    // bijective XCD swizzle (m204): nwg = 9*99 = 891
    const int nwg  = gridDim.x * gridDim.y;
    const int orig = blockIdx.y * gridDim.x + blockIdx.x;
    const int qd = nwg >> 3, r8 = nwg & 7;
    const int xcd = orig & 7, bidx = orig >> 3;
    const int swb = (xcd < r8 ? xcd * (qd + 1) : r8 * (qd + 1) + (xcd - r8) * qd) + bidx;
    const int bx = swb % gridDim.x;
    const int by = swb / gridDim.x;
    const int row0 = by * 256, col0 = bx * 256;

    const int wm = wave >> 2, wn = wave & 3;
    const int q4 = lane >> 4, l15 = lane & 15;
    const int l8 = lane >> 3;
    const int sg = ((lane & 7) ^ ((lane >> 3) & 7)) * 8;   // pre-swizzled src slot

    // staging chunk bases (8-row chunks), 2 instrs per wave per region
    int cA[2], cB[2];
    #pragma unroll
    for (int j = 0; j < 2; ++j) {
        int c = j * 8 + wave;                 // 0..15
        cA[j] = (c >> 3) * 128 + (c & 7) * 8; // A-R0 chunk base (R1: +64)
        cB[j] = (c >> 2) * 64 + (c & 3) * 8;  // B-S0 chunk base (S1: +32)
    }

#define STG_A(buf, kt, roff)                                                   \
    _Pragma("unroll")                                                          \
    for (int j = 0; j < 2; ++j) {                                              \
        int lrow = cA[j] + (roff);                                             \
        int gr = min(row0 + lrow + l8, MROWS - 1);                             \
        gl2lds16(A + (size_t)gr * DIM + (kt) + sg, &Asm[buf][lrow * 64]);      \
    }
#define STG_B(buf, kt, roff)                                                   \
    _Pragma("unroll")                                                          \
    for (int j = 0; j < 2; ++j) {                                              \
        int lrow = cB[j] + (roff);                                             \
        int gr = col0 + lrow + l8;                                             \
        gl2lds16(Bt + (size_t)gr * DIM + (kt) + sg, &Bsm[buf][lrow * 64]);     \
    }

    f32x4 acc[2][4][2][2];
    #pragma unroll
    for (int a = 0; a < 2; ++a)
        #pragma unroll
        for (int b = 0; b < 4; ++b)
            #pragma unroll
            for (int c = 0; c < 2; ++c)
                #pragma unroll
                for (int d = 0; d < 2; ++d)
                    acc[a][b][c][d] = (f32x4){0.f, 0.f, 0.f, 0.f};

    // prologue: steady-state issue order, 14 loads -> vmcnt(6) (drain tile 0)
    STG_A(0, 0, 0);     // t0 A-R0
    STG_B(0, 0, 0);     // t0 B-S0
    STG_A(0, 0, 64);    // t0 A-R1
    STG_B(0, 0, 32);    // t0 B-S1
    STG_A(1, 64, 0);    // t1 A-R0
    STG_B(1, 64, 0);    // t1 B-S0
    STG_A(1, 64, 64);   // t1 A-R1
    asm volatile("s_waitcnt vmcnt(6)" ::: "memory");
    BARRIER_POST();

#define MFMA_Q(AF, BF, MQ, NQ)                                                 \
    __builtin_amdgcn_s_setprio(1);                                             \
    _Pragma("unroll")                                                          \
    for (int kh = 0; kh < 2; ++kh)                                             \
        _Pragma("unroll")                                                      \
        for (int mi = 0; mi < 4; ++mi)                                         \
            _Pragma("unroll")                                                  \
            for (int ni = 0; ni < 2; ++ni)                                     \
                acc[MQ][mi][NQ][ni] = __builtin_amdgcn_mfma_f32_16x16x32_bf16( \
                    AF[kh][mi], BF[kh][ni], acc[MQ][mi][NQ][ni], 0, 0, 0);     \
    __builtin_amdgcn_s_setprio(0);

    for (int T = 0; T < 12; ++T) {
        const int cur = T & 1;
        const ushort_t* Ab = Asm[cur];
        const ushort_t* Bb = Bsm[cur];
        const int kt1 = (T + 1) * 64, kt2 = (T + 2) * 64;
        s16x8 af0[2][4], af1[2][4], bf0[2][2], bf1[2][2];

        // ---- ph0: read af0 (A-R0) + bf0 (B-S0); stage B-S1(t+1)
        #pragma unroll
        for (int kh = 0; kh < 2; ++kh) {
            const int sl = ((kh * 4 + q4) ^ (l15 & 7)) * 8;
            #pragma unroll
            for (int mi = 0; mi < 4; ++mi)
                af0[kh][mi] = *(const s16x8*)&Ab[(wm * 128 + mi * 16 + l15) * 64 + sl];
            #pragma unroll
            for (int ni = 0; ni < 2; ++ni)
                bf0[kh][ni] = *(const s16x8*)&Bb[(wn * 64 + ni * 16 + l15) * 64 + sl];
        }
        if (T + 1 < 12) { STG_B(cur ^ 1, kt1, 32); }
        BARRIER_PRE();
        MFMA_Q(af0, bf0, 0, 0);
        BARRIER_POST();

        // ---- ph1: read bf1 (B-S1); stage A-R0(t+2)
        #pragma unroll
        for (int kh = 0; kh < 2; ++kh) {
            const int sl = ((kh * 4 + q4) ^ (l15 & 7)) * 8;
            #pragma unroll
            for (int ni = 0; ni < 2; ++ni)
                bf1[kh][ni] = *(const s16x8*)&Bb[(wn * 64 + 32 + ni * 16 + l15) * 64 + sl];
        }
        if (T + 2 < 12) { STG_A(cur, kt2, 0); }
        BARRIER_PRE();
        MFMA_Q(af0, bf1, 0, 1);
        BARRIER_POST();

        // ---- ph2: read af1 (A-R1); stage B-S0(t+2)
        #pragma unroll
        for (int kh = 0; kh < 2; ++kh) {
            const int sl = ((kh * 4 + q4) ^ (l15 & 7)) * 8;
            #pragma unroll
            for (int mi = 0; mi < 4; ++mi)
                af1[kh][mi] = *(const s16x8*)&Ab[(wm * 128 + 64 + mi * 16 + l15) * 64 + sl];
        }
        if (T + 2 < 12) { STG_B(cur, kt2, 0); }
        BARRIER_PRE();
        MFMA_Q(af1, bf0, 1, 0);
        BARRIER_POST();

        // ---- ph3: no reads; stage A-R1(t+2); counted vmcnt (once per K-tile)
        if (T + 2 < 12) { STG_A(cur, kt2, 64); }
        if (T < 10)       { asm volatile("s_waitcnt vmcnt(6)" ::: "memory"); }
        else if (T == 10) { asm volatile("s_waitcnt vmcnt(0)" ::: "memory"); }
        BARRIER_PRE();
        MFMA_Q(af1, bf1, 1, 1);
        BARRIER_POST();
    }
#undef STG_A
#undef STG_B
#undef MFMA_Q

    const int colbase = col0 + wn * 64;
    const int seg = colbase / DIM;             // uniform per block (256 | 768)
    const int csub = colbase - seg * DIM;
    ushort_t* outp = (seg == 0) ? q : (seg == 1) ? kk_ : v;
    #pragma unroll
    for (int mq = 0; mq < 2; ++mq) {
        #pragma unroll
        for (int mi = 0; mi < 4; ++mi) {
            #pragma unroll
            for (int nq = 0; nq < 2; ++nq) {
                #pragma unroll
                for (int ni = 0; ni < 2; ++ni) {
                    int gcol = colbase + nq * 32 + ni * 16 + l15;
                    int col  = csub + nq * 32 + ni * 16 + l15;
                    float bb = bias[gcol];
                    #pragma unroll
                    for (int j = 0; j < 4; ++j) {
                        int row = row0 + wm * 128 + mq * 64 + mi * 16 + q4 * 4 + j;
                        if (row < MROWS)
                            outp[(size_t)row * DIM + col] =
                                f2bf(acc[mq][mi][nq][ni][j] + bb);
                    }
                }
            }
        }
    }
}

// ---------------------------------------------------------------------------
// K6: out GEMM via MFMA. A = o bf16, Bt = W_out^T bf16, C fp32.
// 128x128 tile, swizzled LDS (r0 structure).
// ---------------------------------------------------------------------------
__global__ __launch_bounds__(256)
void gemm_out_mfma(const ushort_t* __restrict__ A, const ushort_t* __restrict__ Bt,
                   const float* __restrict__ bias, float* __restrict__ C) {
    const int M = MROWS, N = DIM, K = DIM;
    __shared__ ushort_t Asm[128 * 32];
    __shared__ ushort_t Bsm[128 * 32];
    const int tid  = threadIdx.x;
    const int wave = tid >> 6;
    const int lane = tid & 63;
    const int row0 = blockIdx.y * 128;
    const int col0 = blockIdx.x * 128;
    const int wm = wave >> 1, wn = wave & 1;
    const int q4 = lane >> 4, l15 = lane & 15;
    const int slotg = (lane & 3) ^ ((lane >> 3) & 3);
    const int swz   = (l15 >> 1) & 3;

    f32x4 acc[4][4];
    #pragma unroll
    for (int i = 0; i < 4; ++i)
        #pragma unroll
        for (int j = 0; j < 4; ++j) acc[i][j] = (f32x4){0.f, 0.f, 0.f, 0.f};

    for (int kt = 0; kt < K; kt += 32) {
        #pragma unroll
        for (int r = 0; r < 2; ++r) {
            int seg = r * 4 + wave;
            int rit = seg * 16 + (lane >> 2);
            int grow = min(row0 + rit, M - 1);
            const ushort_t* gp = A + (size_t)grow * K + kt + slotg * 8;
            gl2lds16(gp, &Asm[seg * 512]);
        }
        #pragma unroll
        for (int r = 0; r < 2; ++r) {
            int seg = r * 4 + wave;
            int nit = seg * 16 + (lane >> 2);
            const ushort_t* gp = Bt + (size_t)(col0 + nit) * K + kt + slotg * 8;
            gl2lds16(gp, &Bsm[seg * 512]);
        }
        __syncthreads();
        s16x8 af[4], bfr[4];
        #pragma unroll
        for (int mi = 0; mi < 4; ++mi)
            af[mi] = *(const s16x8*)&Asm[(wm * 64 + mi * 16 + l15) * 32
                                         + ((q4 ^ swz) * 8)];
        #pragma unroll
        for (int ni = 0; ni < 4; ++ni)
            bfr[ni] = *(const s16x8*)&Bsm[(wn * 64 + ni * 16 + l15) * 32
                                          + ((q4 ^ swz) * 8)];
        #pragma unroll
        for (int mi = 0; mi < 4; ++mi)
            #pragma unroll
            for (int ni = 0; ni < 4; ++ni)
                acc[mi][ni] = __builtin_amdgcn_mfma_f32_16x16x32_bf16(
                    af[mi], bfr[ni], acc[mi][ni], 0, 0, 0);
        __syncthreads();
    }
    #pragma unroll
    for (int mi = 0; mi < 4; ++mi) {
        #pragma unroll
        for (int ni = 0; ni < 4; ++ni) {
            int col = col0 + wn * 64 + ni * 16 + l15;
            float bb = bias[col];
            #pragma unroll
            for (int j = 0; j < 4; ++j) {
                int row = row0 + wm * 64 + mi * 16 + q4 * 4 + j;
                if (row < M)
                    C[(size_t)row * N + col] = acc[mi][ni][j] + bb;
            }
        }
    }
}

// ---------------------------------------------------------------------------
// K2: per-(b,c) softmax stats over 785 tokens of k
// ---------------------------------------------------------------------------
__global__ __launch_bounds__(256)
void softmax_stats_kernel(const bf16* __restrict__ k,
                          float* __restrict__ stat_m, float* __restrict__ stat_is) {
    int b = blockIdx.y;
    int c = blockIdx.x * 64 + threadIdx.x;
    int ty = threadIdx.y;
    const bf16* base = k + (size_t)b * NTOK * DIM + c;
    float m = -1e30f, s = 0.f;
    for (int n = ty; n < NTOK; n += 4) {
        float kv = __bfloat162float(base[(size_t)n * DIM]);
        float nm = fmaxf(m, kv);
        s = s * __expf(m - nm) + __expf(kv - nm);
        m = nm;
    }
    __shared__ float sm[4][64], ss[4][64];
    sm[ty][threadIdx.x] = m; ss[ty][threadIdx.x] = s;
    __syncthreads();
    if (ty == 0) {
        float M = sm[0][threadIdx.x];
        #pragma unroll
        for (int i = 1; i < 4; ++i) M = fmaxf(M, sm[i][threadIdx.x]);
        float S = 0.f;
        #pragma unroll
        for (int i = 0; i < 4; ++i) S += ss[i][threadIdx.x] * __expf(sm[i][threadIdx.x] - M);
        stat_m[b * DIM + c] = M;
        stat_is[b * DIM + c] = 1.f / S;
    }
}

// ---------------------------------------------------------------------------
// K3: attn_part[ns][b,h,d,e] = sum_{n in chunk ns} exp(k[n,d]-m_d) * v[n,e]
// ---------------------------------------------------------------------------
__global__ __launch_bounds__(256)
void attn_kernel(const bf16* __restrict__ k, const bf16* __restrict__ v,
                 const float* __restrict__ stat_m,
                 float* __restrict__ attn_part) {
    int h = blockIdx.x, b = blockIdx.y, ns = blockIdx.z;
    int tx = threadIdx.x, ty = threadIdx.y;
    int t = ty * 16 + tx;
    __shared__ float ek[32][98], vv[32][98];
    __shared__ float smM[96];
    if (t < 96) smM[t] = stat_m[b * DIM + h * HD + t];
    __syncthreads();
    float acc[6][6] = {};
    const bf16* kbase = k + (size_t)b * NTOK * DIM + h * HD;
    const bf16* vbase = v + (size_t)b * NTOK * DIM + h * HD;
    const int nlo = ns * NPC;
    const int nhi = min(NTOK, nlo + NPC);
    const int tl = t >> 3;          // token slot 0..31
    const int cg = (t & 7) * 12;    // channel 0,12,..,84
    for (int n0 = nlo; n0 < nhi; n0 += 32) {
        int n = n0 + tl;
        float2 tk[6], tv[6];
        if (n < nhi) {
            #pragma unroll
            for (int j = 0; j < 6; ++j) {
                float2 kf = __bfloat1622float2(
                    *(const __hip_bfloat162*)&kbase[(size_t)n * DIM + cg + 2 * j]);
                float2 vf = __bfloat1622float2(
                    *(const __hip_bfloat162*)&vbase[(size_t)n * DIM + cg + 2 * j]);
                tk[j].x = __expf(kf.x - smM[cg + 2 * j]);
                tk[j].y = __expf(kf.y - smM[cg + 2 * j + 1]);
                tv[j] = vf;
            }
        } else {
            #pragma unroll
            for (int j = 0; j < 6; ++j) {
                tk[j] = make_float2(0.f, 0.f);
                tv[j] = make_float2(0.f, 0.f);
            }
        }
        #pragma unroll
        for (int j = 0; j < 6; ++j) {
            *(float2*)&ek[tl][cg + 2 * j] = tk[j];
            *(float2*)&vv[tl][cg + 2 * j] = tv[j];
        }
        __syncthreads();
        #pragma unroll
        for (int nl = 0; nl < 32; ++nl) {
            float2 ka01 = *(const float2*)&ek[nl][tx * 6];
            float2 ka23 = *(const float2*)&ek[nl][tx * 6 + 2];
            float2 ka45 = *(const float2*)&ek[nl][tx * 6 + 4];
            float2 vb01 = *(const float2*)&vv[nl][ty * 6];
            float2 vb23 = *(const float2*)&vv[nl][ty * 6 + 2];
            float2 vb45 = *(const float2*)&vv[nl][ty * 6 + 4];
            float ka[6] = {ka01.x, ka01.y, ka23.x, ka23.y, ka45.x, ka45.y};
            float vb[6] = {vb01.x, vb01.y, vb23.x, vb23.y, vb45.x, vb45.y};
            #pragma unroll
            for (int i = 0; i < 6; ++i)
                #pragma unroll
                for (int j = 0; j < 6; ++j)
                    acc[i][j] += ka[i] * vb[j];
        }
        __syncthreads();
    }
    float* abase = attn_part + (size_t)ns * BN * NH * HD * HD
                 + ((size_t)(b * NH + h)) * HD * HD;
    #pragma unroll
    for (int i = 0; i < 6; ++i)
        #pragma unroll
        for (int j = 0; j < 6; ++j)
            abase[(size_t)(tx * 6 + i) * HD + ty * 6 + j] = acc[i][j];
}

// ---------------------------------------------------------------------------
// K3b: attn[b,h,d,e] = stat_is[b,h*96+d] * sum_s attn_part[s][b,h,d,e]
// ---------------------------------------------------------------------------
__global__ __launch_bounds__(256)
void attn_reduce_kernel(const float* __restrict__ part,
                        const float* __restrict__ stat_is,
                        float* __restrict__ attn) {
    const int TOT4 = BN * NH * HD * HD / 4;   // 589824
    int i = blockIdx.x * 256 + threadIdx.x;
    if (i >= TOT4) return;
    size_t base = (size_t)i * 4;
    int bh = (int)(base / (HD * HD));
    int d  = (int)((base / HD) % HD);
    float is = stat_is[(bh >> 3) * DIM + (bh & 7) * HD + d];
    const size_t PSZ = (size_t)BN * NH * HD * HD;
    float4 s = *(const float4*)&part[base];
    float4 p1 = *(const float4*)&part[PSZ + base];
    float4 p2 = *(const float4*)&part[2 * PSZ + base];
    float4 p3 = *(const float4*)&part[3 * PSZ + base];
    s.x = (s.x + p1.x + p2.x + p3.x) * is;
    s.y = (s.y + p1.y + p2.y + p3.y) * is;
    s.z = (s.z + p1.z + p2.z + p3.z) * is;
    s.w = (s.w + p1.w + p2.w + p3.w) * is;
    *(float4*)&attn[base] = s;
}

// ---------------------------------------------------------------------------
// K4: CRPE depthwise conv, restructured for occupancy + branch-free taps.
// ---------------------------------------------------------------------------
#define CRS 1104   // conv tile row stride in bf16 elems (34*32 + 16 pad)

template<int KS>
__device__ __forceinline__ void crpe_conv32(const ushort_t* __restrict__ vimg,
                                            const float* __restrict__ wsm,
                                            float b0, float b1,
                                            ushort_t* __restrict__ ob,
                                            int p, int yl, int y) {
    constexpr int R = KS / 2;
    const float* wA = wsm + (2 * p) * KS * KS;
    const float* wB = wA + KS * KS;
    #pragma unroll
    for (int xo = 0; xo < 28; xo += 7) {
        float a0[7], a1[7];
        #pragma unroll
        for (int u = 0; u < 7; ++u) { a0[u] = b0; a1[u] = b1; }
        #pragma unroll
        for (int ky = 0; ky < KS; ++ky) {
            const ushort_t* rp = vimg + (yl + ky - R + 3) * CRS
                                      + (xo - R + 3) * 32 + 2 * p;
            float2 seg[6 + KS];
            #pragma unroll
            for (int i = 0; i < 6 + KS; ++i)
                seg[i] = __bfloat1622float2(*(const __hip_bfloat162*)(rp + i * 32));
            #pragma unroll
            for (int kx = 0; kx < KS; ++kx) {
                float wa = wA[ky * KS + kx];
                float wb = wB[ky * KS + kx];
                #pragma unroll
                for (int u = 0; u < 7; ++u) {
                    a0[u] = fmaf(wa, seg[u + kx].x, a0[u]);
                    a1[u] = fmaf(wb, seg[u + kx].y, a1[u]);
                }
            }
        }
        #pragma unroll
        for (int u = 0; u < 7; ++u)
            *(__hip_bfloat162*)&ob[(size_t)(1 + y * GW + xo + u) * DIM + 2 * p] =
                __float22bfloat162_rn(make_float2(a0[u], a1[u]));
    }
}

__global__ __launch_bounds__(256)
void crpe_lds_kernel(const ushort_t* __restrict__ v,
                     const float* __restrict__ w3, const float* __restrict__ b3,
                     const float* __restrict__ w5, const float* __restrict__ b5,
                     const float* __restrict__ w7, const float* __restrict__ b7,
                     ushort_t* __restrict__ o) {
    __shared__ ushort_t vimg[20 * CRS];   // 44,160 B
    __shared__ float    wsm[32 * 49];     //  6,272 B
    const int cg  = blockIdx.x;    // 0..23, 32-channel group
    const int hf  = blockIdx.y;    // 0..1 image half (rows 0..13 / 14..27)
    const int b   = blockIdx.z;
    const int tid = threadIdx.x;
    const int c0  = cg * 32;

    const float* wsrc; const float* bsrc; int ks;
    if (c0 < 192)      { wsrc = w3 + c0 * 9;          bsrc = b3 + c0;         ks = 3; }
    else if (c0 < 480) { wsrc = w5 + (c0 - 192) * 25; bsrc = b5 + (c0 - 192); ks = 5; }
    else               { wsrc = w7 + (c0 - 480) * 49; bsrc = b7 + (c0 - 480); ks = 7; }
    const int ksq = ks * ks;

    const int zr0 = hf ? 17 : 0;
    for (int idx = tid; idx < 3 * 138; idx += 256) {
        int rr = idx / 138, cc = idx - rr * 138;
        *(s16x8*)&vimg[(zr0 + rr) * CRS + cc * 8] = (s16x8){0,0,0,0,0,0,0,0};
    }
    for (int idx = tid; idx < 17 * 24; idx += 256) {
        int vr = idx / 24, cc = idx - vr * 24;
        int ly = hf ? vr : vr + 3;
        int ch = (cc < 12) ? cc : (112 + cc);
        *(s16x8*)&vimg[ly * CRS + ch * 8] = (s16x8){0,0,0,0,0,0,0,0};
    }
    for (int idx = tid; idx < 32 * ksq; idx += 256)
        wsm[idx] = wsrc[idx];
    const ushort_t* vb = v + (size_t)b * NTOK * DIM + c0;
    const int gy0 = hf ? 11 : 0;
    for (int idx = tid; idx < 17 * 28 * 4; idx += 256) {
        int vr = idx / 112, rem = idx - vr * 112;
        int px = rem >> 2, c8 = rem & 3;
        int gy = gy0 + vr;
        int ly = hf ? vr : vr + 3;
        *(s16x8*)&vimg[ly * CRS + (px + 3) * 32 + c8 * 8] =
            *(const s16x8*)(vb + (size_t)(1 + gy * GW + px) * DIM + c8 * 8);
    }
    ushort_t* ob = o + (size_t)b * NTOK * DIM + c0;
    if (hf == 0 && tid < 32) ob[tid] = 0;   // CLS row: rp = 0
    __syncthreads();

    const int p  = tid & 15;       // channel pair 0..15
    const int yl = tid >> 4;       // row within half 0..15
    if (yl >= 14) return;
    const int y = hf * 14 + yl;    // global row
    float bb0 = bsrc[2 * p], bb1 = bsrc[2 * p + 1];
    if (ks == 3)      crpe_conv32<3>(vimg, wsm, bb0, bb1, ob, p, yl, y);
    else if (ks == 5) crpe_conv32<5>(vimg, wsm, bb0, bb1, ob, p, yl, y);
    else              crpe_conv32<7>(vimg, wsm, bb0, bb1, ob, p, yl, y);
}

// ---------------------------------------------------------------------------
// K5: o[b,n,h*96+e] = scale * sum_d q[n,d] attn[d,e] + q[n,e] * rp (in-place)
// ---------------------------------------------------------------------------
__global__ __launch_bounds__(256)
void combine_kernel(const bf16* __restrict__ q, const float* __restrict__ attn,
                    bf16* __restrict__ o) {
    int h = blockIdx.x;
    int n0 = blockIdx.y * 64;
    int b = blockIdx.z;
    int tx = threadIdx.x, ty = threadIdx.y;
    int t = ty * 16 + tx;
    __shared__ float as[96][96];
    __shared__ float qs[64][97];
    const float* abase = attn + ((size_t)(b * NH + h)) * HD * HD;
    #pragma unroll
    for (int i = 0; i < 36; ++i) {
        int idx = t + i * 256;
        as[idx / 96][idx % 96] = abase[idx];
    }
    const bf16* qbase = q + (size_t)b * NTOK * DIM + h * HD;
    #pragma unroll
    for (int i = 0; i < 24; ++i) {
        int idx = t + i * 256;
        int rr = idx / 96, cc = idx % 96;
        int n = n0 + rr;
        qs[rr][cc] = (n < NTOK) ? __bfloat162float(qbase[(size_t)n * DIM + cc]) : 0.f;
    }
    __syncthreads();
    float acc[4][6] = {};
    for (int d = 0; d < 96; ++d) {
        float qa[4], ab[6];
        #pragma unroll
        for (int i = 0; i < 4; ++i) qa[i] = qs[ty * 4 + i][d];
        #pragma unroll
        for (int j = 0; j < 6; ++j) ab[j] = as[d][tx * 6 + j];
        #pragma unroll
        for (int i = 0; i < 4; ++i)
            #pragma unroll
            for (int j = 0; j < 6; ++j)
                acc[i][j] += qa[i] * ab[j];
    }
    const float scale = 0.10206207261596575f;  // 96^-0.5
    bf16* obase = o + (size_t)b * NTOK * DIM + h * HD;
    #pragma unroll
    for (int i = 0; i < 4; ++i) {
        int n = n0 + ty * 4 + i;
        if (n >= NTOK) continue;
        #pragma unroll
        for (int j = 0; j < 6; ++j) {
            int e = tx * 6 + j;
            size_t oa = (size_t)n * DIM + e;
            float rp = __bfloat162float(obase[oa]);
            float qv = qs[ty * 4 + i][e];
            obase[oa] = __float2bfloat16(scale * acc[i][j] + qv * rp);
        }
    }
}

// ---------------------------------------------------------------------------
extern "C" void kernel_launch(void* const* d_in, const int* in_sizes, int n_in,
                              void* d_out, int out_size, void* d_ws, size_t ws_size,
                              hipStream_t stream) {
    const float* x     = (const float*)d_in[0];
    const float* W_qkv = (const float*)d_in[1];
    const float* b_qkv = (const float*)d_in[2];
    const float* W_out = (const float*)d_in[3];
    const float* b_out = (const float*)d_in[4];
    const float* w3    = (const float*)d_in[5];
    const float* cb3   = (const float*)d_in[6];
    const float* w5    = (const float*)d_in[7];
    const float* cb5   = (const float*)d_in[8];
    const float* w7    = (const float*)d_in[9];
    const float* cb7   = (const float*)d_in[10];
    float* out = (float*)d_out;

    ushort_t* q = (ushort_t*)d_ws;
    ushort_t* k = q + (size_t)MROWS * DIM;
    ushort_t* v = k + (size_t)MROWS * DIM;
    float* attn    = (float*)(v + (size_t)MROWS * DIM);
    float* stat_m  = attn + (size_t)BN * NH * HD * HD;
    float* stat_is = stat_m + (size_t)BN * DIM;
    ushort_t* Wqkvt = (ushort_t*)(stat_is + (size_t)BN * DIM);
    ushort_t* Wot   = Wqkvt + (size_t)QKVD * DIM;
    ushort_t* o = k;   // alias: k dead after attn_kernel

    // d_out scratch layout: xb (bf16 x, 38.58 MB) then attn_part (37.75 MB).
    // Both dead before gemm_out_mfma writes d_out (77.17 MB total).
    ushort_t* xb = (ushort_t*)d_out;
    float* attn_part = (float*)d_out + (size_t)MROWS * DIM / 2;

    transpose_bf16_kernel<<<dim3(QKVD / 32, DIM / 32), dim3(32, 8), 0, stream>>>(
        W_qkv, Wqkvt, DIM, QKVD);
    transpose_bf16_kernel<<<dim3(DIM / 32, DIM / 32), dim3(32, 8), 0, stream>>>(
        W_out, Wot, DIM, DIM);
    {
        int n8 = MROWS * DIM / 8;
        f32_to_bf16_kernel<<<dim3((n8 + 255) / 256), 256, 0, stream>>>(x, xb, n8);
    }
    gemm_qkv_256<<<dim3(QKVD / 256, (MROWS + 255) / 256), 512, 0, stream>>>(
        xb, Wqkvt, b_qkv, q, k, v);
    softmax_stats_kernel<<<dim3(12, BN), dim3(64, 4), 0, stream>>>(
        (const bf16*)k, stat_m, stat_is);
    attn_kernel<<<dim3(NH, BN, NS), dim3(16, 16), 0, stream>>>(
        (const bf16*)k, (const bf16*)v, stat_m, attn_part);
    {
        int tot4 = BN * NH * HD * HD / 4;
        attn_reduce_kernel<<<dim3((tot4 + 255) / 256), 256, 0, stream>>>(
            attn_part, stat_is, attn);
    }
    crpe_lds_kernel<<<dim3(24, 2, BN), 256, 0, stream>>>(
        v, w3, cb3, w5, cb5, w7, cb7, o);
    combine_kernel<<<dim3(NH, 13, BN), dim3(16, 16), 0, stream>>>(
        (const bf16*)q, attn, (bf16*)o);
    gemm_out_mfma<<<dim3(DIM / 128, (MROWS + 127) / 128), 256, 0, stream>>>(
        o, Wot, b_out, out);
}

// Round 6
// 564.250 us; speedup vs baseline: 1.2152x; 1.2092x over previous
//
#include <hip/hip_runtime.h>
#include <hip/hip_bf16.h>
#include <math.h>

#define BN    32
#define NTOK  785
#define GH    28
#define GW    28
#define DIM   768
#define QKVD  2304
#define NH    8
#define HD    96
#define MROWS (BN*NTOK)   // 25120
#define NS    4           // attn token-split
#define NPC   197         // ceil(785/4)

typedef __hip_bfloat16 bf16;
typedef unsigned short ushort_t;
typedef short s16x8 __attribute__((ext_vector_type(8)));   // 8 bf16 = 4 VGPRs
typedef float f32x4 __attribute__((ext_vector_type(4)));   // MFMA acc

// ---------------------------------------------------------------------------
// helpers
// ---------------------------------------------------------------------------
__device__ __forceinline__ void gl2lds16(const void* g, void* l) {
    // 16B per lane, LDS dest = wave-uniform base + lane*16
    __builtin_amdgcn_global_load_lds(
        (__attribute__((address_space(1))) void*)const_cast<void*>(g),
        (__attribute__((address_space(3))) void*)l, 16, 0, 0);
}

__device__ __forceinline__ ushort_t f2bf(float f) {
    bf16 h = __float2bfloat16(f);
    return *(ushort_t*)&h;
}

__device__ __forceinline__ s16x8 cvt8(const float* p) {   // 8 fp32 (LDS) -> bf16x8
    float4 a = *(const float4*)p;
    float4 b = *(const float4*)(p + 4);
    union { s16x8 v; __hip_bfloat162 h[4]; } r;
    r.h[0] = __float22bfloat162_rn(make_float2(a.x, a.y));
    r.h[1] = __float22bfloat162_rn(make_float2(a.z, a.w));
    r.h[2] = __float22bfloat162_rn(make_float2(b.x, b.y));
    r.h[3] = __float22bfloat162_rn(make_float2(b.z, b.w));
    return r.v;
}

// ---------------------------------------------------------------------------
// K-1: fp32 -> bf16 convert (x -> xb). 8 elems/thread, vectorized.
// ---------------------------------------------------------------------------
__global__ __launch_bounds__(256)
void f32_to_bf16_kernel(const float* __restrict__ in, ushort_t* __restrict__ out,
                        int n8) {
    int i = blockIdx.x * 256 + threadIdx.x;
    if (i >= n8) return;
    const float4* p = (const float4*)(in + (size_t)i * 8);
    float4 a = p[0], b = p[1];
    union { s16x8 v; __hip_bfloat162 h[4]; } r;
    r.h[0] = __float22bfloat162_rn(make_float2(a.x, a.y));
    r.h[1] = __float22bfloat162_rn(make_float2(a.z, a.w));
    r.h[2] = __float22bfloat162_rn(make_float2(b.x, b.y));
    r.h[3] = __float22bfloat162_rn(make_float2(b.z, b.w));
    *(s16x8*)(out + (size_t)i * 8) = r.v;
}

// ---------------------------------------------------------------------------
// K0: transpose-convert W[R][C] fp32 -> Wt[C][R] bf16
// ---------------------------------------------------------------------------
__global__ __launch_bounds__(256)
void transpose_bf16_kernel(const float* __restrict__ W, ushort_t* __restrict__ Wt,
                           int R, int C) {
    __shared__ float tile[32][33];
    int c0 = blockIdx.x * 32, r0 = blockIdx.y * 32;
    int tx = threadIdx.x, ty = threadIdx.y;   // 32 x 8
    #pragma unroll
    for (int i = 0; i < 4; ++i)
        tile[ty + i * 8][tx] = W[(size_t)(r0 + ty + i * 8) * C + c0 + tx];
    __syncthreads();
    #pragma unroll
    for (int i = 0; i < 4; ++i)
        Wt[(size_t)(c0 + ty + i * 8) * R + r0 + tx] = f2bf(tile[tx][ty + i * 8]);
}

// ---------------------------------------------------------------------------
// K1: qkv GEMM via MFMA (PROVEN r3 version, 148 us). A = xb bf16 [M][768],
// Bt = W_qkv^T bf16 [2304][768]. 128x128 tile, BK=32, 4 waves, 16x16x32 MFMA.
// XOR-swizzled LDS, both-sides (rule #21).
// ---------------------------------------------------------------------------
__global__ __launch_bounds__(256)
void gemm_qkv_mfma(const ushort_t* __restrict__ A, const ushort_t* __restrict__ Bt,
                   const float* __restrict__ bias,
                   ushort_t* __restrict__ q, ushort_t* __restrict__ kk,
                   ushort_t* __restrict__ v) {
    const int M = MROWS, K = DIM;
    __shared__ ushort_t Asm[128 * 32];   // 8 KB
    __shared__ ushort_t Bsm[128 * 32];   // 8 KB
    const int tid  = threadIdx.x;
    const int wave = tid >> 6;
    const int lane = tid & 63;
    const int row0 = blockIdx.y * 128;
    const int col0 = blockIdx.x * 128;
    const int wm = wave >> 1, wn = wave & 1;
    const int q4 = lane >> 4, l15 = lane & 15;
    const int slotg = (lane & 3) ^ ((lane >> 3) & 3);  // staging source slot
    const int swz   = (l15 >> 1) & 3;                  // read-side row xor

    f32x4 acc[4][4];
    #pragma unroll
    for (int i = 0; i < 4; ++i)
        #pragma unroll
        for (int j = 0; j < 4; ++j) acc[i][j] = (f32x4){0.f, 0.f, 0.f, 0.f};

    for (int kt = 0; kt < K; kt += 32) {
        #pragma unroll
        for (int r = 0; r < 2; ++r) {
            int seg = r * 4 + wave;
            int rit = seg * 16 + (lane >> 2);
            int grow = min(row0 + rit, M - 1);
            const ushort_t* gp = A + (size_t)grow * K + kt + slotg * 8;
            gl2lds16(gp, &Asm[seg * 512]);
        }
        #pragma unroll
        for (int r = 0; r < 2; ++r) {
            int seg = r * 4 + wave;
            int nit = seg * 16 + (lane >> 2);
            const ushort_t* gp = Bt + (size_t)(col0 + nit) * K + kt + slotg * 8;
            gl2lds16(gp, &Bsm[seg * 512]);
        }
        __syncthreads();
        s16x8 af[4], bfr[4];
        #pragma unroll
        for (int mi = 0; mi < 4; ++mi)
            af[mi] = *(const s16x8*)&Asm[(wm * 64 + mi * 16 + l15) * 32
                                         + ((q4 ^ swz) * 8)];
        #pragma unroll
        for (int ni = 0; ni < 4; ++ni)
            bfr[ni] = *(const s16x8*)&Bsm[(wn * 64 + ni * 16 + l15) * 32
                                          + ((q4 ^ swz) * 8)];
        #pragma unroll
        for (int mi = 0; mi < 4; ++mi)
            #pragma unroll
            for (int ni = 0; ni < 4; ++ni)
                acc[mi][ni] = __builtin_amdgcn_mfma_f32_16x16x32_bf16(
                    af[mi], bfr[ni], acc[mi][ni], 0, 0, 0);
        __syncthreads();
    }
    int colbase = col0 + wn * 64;
    int seg = colbase / DIM;
    int csub = colbase - seg * DIM;
    ushort_t* outp = (seg == 0) ? q : (seg == 1) ? kk : v;
    #pragma unroll
    for (int mi = 0; mi < 4; ++mi) {
        #pragma unroll
        for (int ni = 0; ni < 4; ++ni) {
            int gcol = colbase + ni * 16 + l15;
            int col  = csub + ni * 16 + l15;
            float bb = bias[gcol];
            #pragma unroll
            for (int j = 0; j < 4; ++j) {
                int row = row0 + wm * 64 + mi * 16 + q4 * 4 + j;
                if (row < M)
                    outp[(size_t)row * DIM + col] = f2bf(acc[mi][ni][j] + bb);
            }
        }
    }
}

// ---------------------------------------------------------------------------
// K6: out GEMM via MFMA. A = o bf16, Bt = W_out^T bf16, C fp32.
// Same swizzled-LDS structure as K1.
// ---------------------------------------------------------------------------
__global__ __launch_bounds__(256)
void gemm_out_mfma(const ushort_t* __restrict__ A, const ushort_t* __restrict__ Bt,
                   const float* __restrict__ bias, float* __restrict__ C) {
    const int M = MROWS, N = DIM, K = DIM;
    __shared__ ushort_t Asm[128 * 32];
    __shared__ ushort_t Bsm[128 * 32];
    const int tid  = threadIdx.x;
    const int wave = tid >> 6;
    const int lane = tid & 63;
    const int row0 = blockIdx.y * 128;
    const int col0 = blockIdx.x * 128;
    const int wm = wave >> 1, wn = wave & 1;
    const int q4 = lane >> 4, l15 = lane & 15;
    const int slotg = (lane & 3) ^ ((lane >> 3) & 3);
    const int swz   = (l15 >> 1) & 3;

    f32x4 acc[4][4];
    #pragma unroll
    for (int i = 0; i < 4; ++i)
        #pragma unroll
        for (int j = 0; j < 4; ++j) acc[i][j] = (f32x4){0.f, 0.f, 0.f, 0.f};

    for (int kt = 0; kt < K; kt += 32) {
        #pragma unroll
        for (int r = 0; r < 2; ++r) {
            int seg = r * 4 + wave;
            int rit = seg * 16 + (lane >> 2);
            int grow = min(row0 + rit, M - 1);
            const ushort_t* gp = A + (size_t)grow * K + kt + slotg * 8;
            gl2lds16(gp, &Asm[seg * 512]);
        }
        #pragma unroll
        for (int r = 0; r < 2; ++r) {
            int seg = r * 4 + wave;
            int nit = seg * 16 + (lane >> 2);
            const ushort_t* gp = Bt + (size_t)(col0 + nit) * K + kt + slotg * 8;
            gl2lds16(gp, &Bsm[seg * 512]);
        }
        __syncthreads();
        s16x8 af[4], bfr[4];
        #pragma unroll
        for (int mi = 0; mi < 4; ++mi)
            af[mi] = *(const s16x8*)&Asm[(wm * 64 + mi * 16 + l15) * 32
                                         + ((q4 ^ swz) * 8)];
        #pragma unroll
        for (int ni = 0; ni < 4; ++ni)
            bfr[ni] = *(const s16x8*)&Bsm[(wn * 64 + ni * 16 + l15) * 32
                                          + ((q4 ^ swz) * 8)];
        #pragma unroll
        for (int mi = 0; mi < 4; ++mi)
            #pragma unroll
            for (int ni = 0; ni < 4; ++ni)
                acc[mi][ni] = __builtin_amdgcn_mfma_f32_16x16x32_bf16(
                    af[mi], bfr[ni], acc[mi][ni], 0, 0, 0);
        __syncthreads();
    }
    #pragma unroll
    for (int mi = 0; mi < 4; ++mi) {
        #pragma unroll
        for (int ni = 0; ni < 4; ++ni) {
            int col = col0 + wn * 64 + ni * 16 + l15;
            float bb = bias[col];
            #pragma unroll
            for (int j = 0; j < 4; ++j) {
                int row = row0 + wm * 64 + mi * 16 + q4 * 4 + j;
                if (row < M)
                    C[(size_t)row * N + col] = acc[mi][ni][j] + bb;
            }
        }
    }
}

// ---------------------------------------------------------------------------
// K2: per-(b,c) softmax stats over 785 tokens of k
// ---------------------------------------------------------------------------
__global__ __launch_bounds__(256)
void softmax_stats_kernel(const bf16* __restrict__ k,
                          float* __restrict__ stat_m, float* __restrict__ stat_is) {
    int b = blockIdx.y;
    int c = blockIdx.x * 64 + threadIdx.x;
    int ty = threadIdx.y;
    const bf16* base = k + (size_t)b * NTOK * DIM + c;
    float m = -1e30f, s = 0.f;
    for (int n = ty; n < NTOK; n += 4) {
        float kv = __bfloat162float(base[(size_t)n * DIM]);
        float nm = fmaxf(m, kv);
        s = s * __expf(m - nm) + __expf(kv - nm);
        m = nm;
    }
    __shared__ float sm[4][64], ss[4][64];
    sm[ty][threadIdx.x] = m; ss[ty][threadIdx.x] = s;
    __syncthreads();
    if (ty == 0) {
        float M = sm[0][threadIdx.x];
        #pragma unroll
        for (int i = 1; i < 4; ++i) M = fmaxf(M, sm[i][threadIdx.x]);
        float S = 0.f;
        #pragma unroll
        for (int i = 0; i < 4; ++i) S += ss[i][threadIdx.x] * __expf(sm[i][threadIdx.x] - M);
        stat_m[b * DIM + c] = M;
        stat_is[b * DIM + c] = 1.f / S;
    }
}

// ---------------------------------------------------------------------------
// K3: attn_part[ns][b,h,d,e] = sum_{n in chunk} exp(k[n,d]-m_d) * v[n,e]
// MFMA version: C = Ek^T * V. Both operands staged TRANSPOSED in LDS as f32
// ([96 ch][36 tok] rows, 144B stride: 16B-aligned, 2-way banks on b128 reads),
// converted to bf16 fragments via cvt8 at read. Fragment pattern copied from
// the verified GEMM: A,B stored [dim][k], read (l15 -> dim, q4*8 -> k);
// C: col=lane&15, row=(lane>>4)*4+reg. 4 waves = 2x2 quadrants of 48x48.
// ---------------------------------------------------------------------------
__global__ __launch_bounds__(256)
void attn_kernel(const bf16* __restrict__ k, const bf16* __restrict__ v,
                 const float* __restrict__ stat_m,
                 float* __restrict__ attn_part) {
    const int h = blockIdx.x, b = blockIdx.y, ns = blockIdx.z;
    const int t = threadIdx.x;
    const int wave = t >> 6, lane = t & 63;
    const int q4 = lane >> 4, l15 = lane & 15;
    const int wd = wave >> 1, we = wave & 1;   // quadrant: d-half, e-half
    __shared__ float ekT[96][36];
    __shared__ float vT[96][36];
    __shared__ float smM[96];
    if (t < 96) smM[t] = stat_m[b * DIM + h * HD + t];
    __syncthreads();

    f32x4 acc[3][3];
    #pragma unroll
    for (int i = 0; i < 3; ++i)
        #pragma unroll
        for (int j = 0; j < 3; ++j) acc[i][j] = (f32x4){0.f, 0.f, 0.f, 0.f};

    const bf16* kbase = k + (size_t)b * NTOK * DIM + h * HD;
    const bf16* vbase = v + (size_t)b * NTOK * DIM + h * HD;
    const int nlo = ns * NPC;
    const int nhi = min(NTOK, nlo + NPC);
    const int tl = t >> 3;          // token slot 0..31
    const int cg = (t & 7) * 12;    // channel base 0,12,..,84
    for (int n0 = nlo; n0 < nhi; n0 += 32) {
        const int n = n0 + tl;
        if (n < nhi) {
            #pragma unroll
            for (int j = 0; j < 6; ++j) {
                float2 kf = __bfloat1622float2(
                    *(const __hip_bfloat162*)&kbase[(size_t)n * DIM + cg + 2 * j]);
                float2 vf = __bfloat1622float2(
                    *(const __hip_bfloat162*)&vbase[(size_t)n * DIM + cg + 2 * j]);
                ekT[cg + 2 * j][tl]     = __expf(kf.x - smM[cg + 2 * j]);
                ekT[cg + 2 * j + 1][tl] = __expf(kf.y - smM[cg + 2 * j + 1]);
                vT[cg + 2 * j][tl]      = vf.x;
                vT[cg + 2 * j + 1][tl]  = vf.y;
            }
        } else {
            #pragma unroll
            for (int j = 0; j < 12; ++j) {
                ekT[cg + j][tl] = 0.f;
                vT[cg + j][tl]  = 0.f;
            }
        }
        __syncthreads();
        s16x8 af[3], bfr[3];
        #pragma unroll
        for (int i = 0; i < 3; ++i)
            af[i] = cvt8(&ekT[wd * 48 + i * 16 + l15][q4 * 8]);
        #pragma unroll
        for (int i = 0; i < 3; ++i)
            bfr[i] = cvt8(&vT[we * 48 + i * 16 + l15][q4 * 8]);
        #pragma unroll
        for (int i = 0; i < 3; ++i)
            #pragma unroll
            for (int j = 0; j < 3; ++j)
                acc[i][j] = __builtin_amdgcn_mfma_f32_16x16x32_bf16(
                    af[i], bfr[j], acc[i][j], 0, 0, 0);
        __syncthreads();
    }
    float* abase = attn_part + (size_t)ns * BN * NH * HD * HD
                 + (size_t)(b * NH + h) * HD * HD;
    #pragma unroll
    for (int i = 0; i < 3; ++i)
        #pragma unroll
        for (int j = 0; j < 3; ++j)
            #pragma unroll
            for (int r = 0; r < 4; ++r)
                abase[(size_t)(wd * 48 + i * 16 + q4 * 4 + r) * HD
                      + we * 48 + j * 16 + l15] = acc[i][j][r];
}

// ---------------------------------------------------------------------------
// K3b: attn[b,h,d,e] = stat_is[b,h*96+d] * sum_s attn_part[s][b,h,d,e]
// ---------------------------------------------------------------------------
__global__ __launch_bounds__(256)
void attn_reduce_kernel(const float* __restrict__ part,
                        const float* __restrict__ stat_is,
                        float* __restrict__ attn) {
    const int TOT4 = BN * NH * HD * HD / 4;   // 589824
    int i = blockIdx.x * 256 + threadIdx.x;
    if (i >= TOT4) return;
    size_t base = (size_t)i * 4;
    int bh = (int)(base / (HD * HD));
    int d  = (int)((base / HD) % HD);
    float is = stat_is[(bh >> 3) * DIM + (bh & 7) * HD + d];
    const size_t PSZ = (size_t)BN * NH * HD * HD;
    float4 s = *(const float4*)&part[base];
    float4 p1 = *(const float4*)&part[PSZ + base];
    float4 p2 = *(const float4*)&part[2 * PSZ + base];
    float4 p3 = *(const float4*)&part[3 * PSZ + base];
    s.x = (s.x + p1.x + p2.x + p3.x) * is;
    s.y = (s.y + p1.y + p2.y + p3.y) * is;
    s.z = (s.z + p1.z + p2.z + p3.z) * is;
    s.w = (s.w + p1.w + p2.w + p3.w) * is;
    *(float4*)&attn[base] = s;
}

// ---------------------------------------------------------------------------
// K4: CRPE depthwise conv, restructured for occupancy + branch-free taps.
// ---------------------------------------------------------------------------
#define CRS 1104   // conv tile row stride in bf16 elems (34*32 + 16 pad)

template<int KS>
__device__ __forceinline__ void crpe_conv32(const ushort_t* __restrict__ vimg,
                                            const float* __restrict__ wsm,
                                            float b0, float b1,
                                            ushort_t* __restrict__ ob,
                                            int p, int yl, int y) {
    constexpr int R = KS / 2;
    const float* wA = wsm + (2 * p) * KS * KS;
    const float* wB = wA + KS * KS;
    #pragma unroll
    for (int xo = 0; xo < 28; xo += 7) {
        float a0[7], a1[7];
        #pragma unroll
        for (int u = 0; u < 7; ++u) { a0[u] = b0; a1[u] = b1; }
        #pragma unroll
        for (int ky = 0; ky < KS; ++ky) {
            const ushort_t* rp = vimg + (yl + ky - R + 3) * CRS
                                      + (xo - R + 3) * 32 + 2 * p;
            float2 seg[6 + KS];
            #pragma unroll
            for (int i = 0; i < 6 + KS; ++i)
                seg[i] = __bfloat1622float2(*(const __hip_bfloat162*)(rp + i * 32));
            #pragma unroll
            for (int kx = 0; kx < KS; ++kx) {
                float wa = wA[ky * KS + kx];
                float wb = wB[ky * KS + kx];
                #pragma unroll
                for (int u = 0; u < 7; ++u) {
                    a0[u] = fmaf(wa, seg[u + kx].x, a0[u]);
                    a1[u] = fmaf(wb, seg[u + kx].y, a1[u]);
                }
            }
        }
        #pragma unroll
        for (int u = 0; u < 7; ++u)
            *(__hip_bfloat162*)&ob[(size_t)(1 + y * GW + xo + u) * DIM + 2 * p] =
                __float22bfloat162_rn(make_float2(a0[u], a1[u]));
    }
}

__global__ __launch_bounds__(256)
void crpe_lds_kernel(const ushort_t* __restrict__ v,
                     const float* __restrict__ w3, const float* __restrict__ b3,
                     const float* __restrict__ w5, const float* __restrict__ b5,
                     const float* __restrict__ w7, const float* __restrict__ b7,
                     ushort_t* __restrict__ o) {
    __shared__ ushort_t vimg[20 * CRS];   // 44,160 B
    __shared__ float    wsm[32 * 49];     //  6,272 B
    const int cg  = blockIdx.x;    // 0..23, 32-channel group
    const int hf  = blockIdx.y;    // 0..1 image half (rows 0..13 / 14..27)
    const int b   = blockIdx.z;
    const int tid = threadIdx.x;
    const int c0  = cg * 32;

    const float* wsrc; const float* bsrc; int ks;
    if (c0 < 192)      { wsrc = w3 + c0 * 9;          bsrc = b3 + c0;         ks = 3; }
    else if (c0 < 480) { wsrc = w5 + (c0 - 192) * 25; bsrc = b5 + (c0 - 192); ks = 5; }
    else               { wsrc = w7 + (c0 - 480) * 49; bsrc = b7 + (c0 - 480); ks = 7; }
    const int ksq = ks * ks;

    const int zr0 = hf ? 17 : 0;
    for (int idx = tid; idx < 3 * 138; idx += 256) {
        int rr = idx / 138, cc = idx - rr * 138;
        *(s16x8*)&vimg[(zr0 + rr) * CRS + cc * 8] = (s16x8){0,0,0,0,0,0,0,0};
    }
    for (int idx = tid; idx < 17 * 24; idx += 256) {
        int vr = idx / 24, cc = idx - vr * 24;
        int ly = hf ? vr : vr + 3;
        int ch = (cc < 12) ? cc : (112 + cc);
        *(s16x8*)&vimg[ly * CRS + ch * 8] = (s16x8){0,0,0,0,0,0,0,0};
    }
    for (int idx = tid; idx < 32 * ksq; idx += 256)
        wsm[idx] = wsrc[idx];
    const ushort_t* vb = v + (size_t)b * NTOK * DIM + c0;
    const int gy0 = hf ? 11 : 0;
    for (int idx = tid; idx < 17 * 28 * 4; idx += 256) {
        int vr = idx / 112, rem = idx - vr * 112;
        int px = rem >> 2, c8 = rem & 3;
        int gy = gy0 + vr;
        int ly = hf ? vr : vr + 3;
        *(s16x8*)&vimg[ly * CRS + (px + 3) * 32 + c8 * 8] =
            *(const s16x8*)(vb + (size_t)(1 + gy * GW + px) * DIM + c8 * 8);
    }
    ushort_t* ob = o + (size_t)b * NTOK * DIM + c0;
    if (hf == 0 && tid < 32) ob[tid] = 0;   // CLS row: rp = 0
    __syncthreads();

    const int p  = tid & 15;       // channel pair 0..15
    const int yl = tid >> 4;       // row within half 0..15
    if (yl >= 14) return;
    const int y = hf * 14 + yl;    // global row
    float bb0 = bsrc[2 * p], bb1 = bsrc[2 * p + 1];
    if (ks == 3)      crpe_conv32<3>(vimg, wsm, bb0, bb1, ob, p, yl, y);
    else if (ks == 5) crpe_conv32<5>(vimg, wsm, bb0, bb1, ob, p, yl, y);
    else              crpe_conv32<7>(vimg, wsm, bb0, bb1, ob, p, yl, y);
}

// ---------------------------------------------------------------------------
// K5: o[b,n,h*96+e] = scale * sum_d q[n,d] attn[d,e] + q[n,e] * rp (in-place)
// MFMA version: A = q tile [64 n][96 d] bf16 (frags read directly, no cvt);
// B = attn transposed -> bf16 [96 e][96 d] (stride 104 ush = 208B: aligned,
// ~2-way banks). 4 waves = 4 m-tiles of 16 rows; 6 e-tiles each; K=96 (3 steps).
// ---------------------------------------------------------------------------
__global__ __launch_bounds__(256)
void combine_kernel(const ushort_t* __restrict__ q, const float* __restrict__ attn,
                    ushort_t* __restrict__ o) {
    const int h = blockIdx.x, b = blockIdx.z;
    const int n0 = blockIdx.y * 64;
    const int t = threadIdx.x;
    const int wave = t >> 6, lane = t & 63;
    const int q4 = lane >> 4, l15 = lane & 15;
    __shared__ ushort_t qs[64][104];
    __shared__ ushort_t atT[96][104];

    const ushort_t* qbase = q + (size_t)b * NTOK * DIM + h * HD;
    #pragma unroll
    for (int i = 0; i < 3; ++i) {
        int idx = t + i * 256;          // 0..767 = 64 rows x 12 chunks
        int rr = idx / 12, c8 = idx % 12;
        int n = n0 + rr;
        s16x8 val = (s16x8){0,0,0,0,0,0,0,0};
        if (n < NTOK) val = *(const s16x8*)(qbase + (size_t)n * DIM + c8 * 8);
        *(s16x8*)&qs[rr][c8 * 8] = val;
    }
    const float* abase = attn + (size_t)(b * NH + h) * HD * HD;
    #pragma unroll
    for (int i = 0; i < 36; ++i) {
        int idx = t + i * 256;          // 0..9215; read coalesced [d][e]
        int d = idx / 96, e = idx % 96;
        atT[e][d] = f2bf(abase[idx]);
    }
    __syncthreads();

    f32x4 acc[6];
    #pragma unroll
    for (int i = 0; i < 6; ++i) acc[i] = (f32x4){0.f, 0.f, 0.f, 0.f};
    #pragma unroll
    for (int ks = 0; ks < 3; ++ks) {
        s16x8 aq = *(const s16x8*)&qs[wave * 16 + l15][ks * 32 + q4 * 8];
        #pragma unroll
        for (int et = 0; et < 6; ++et) {
            s16x8 bfrg = *(const s16x8*)&atT[et * 16 + l15][ks * 32 + q4 * 8];
            acc[et] = __builtin_amdgcn_mfma_f32_16x16x32_bf16(
                aq, bfrg, acc[et], 0, 0, 0);
        }
    }

    const float scale = 0.10206207261596575f;  // 96^-0.5
    ushort_t* obase = o + (size_t)b * NTOK * DIM + h * HD;
    #pragma unroll
    for (int et = 0; et < 6; ++et) {
        int e = et * 16 + l15;
        #pragma unroll
        for (int r = 0; r < 4; ++r) {
            int rr = wave * 16 + q4 * 4 + r;
            int n = n0 + rr;
            if (n >= NTOK) continue;
            size_t oa = (size_t)n * DIM + e;
            float rp = __bfloat162float(*(const bf16*)&obase[oa]);
            float qv = __bfloat162float(*(const bf16*)&qs[rr][e]);
            obase[oa] = f2bf(scale * acc[et][r] + qv * rp);
        }
    }
}

// ---------------------------------------------------------------------------
extern "C" void kernel_launch(void* const* d_in, const int* in_sizes, int n_in,
                              void* d_out, int out_size, void* d_ws, size_t ws_size,
                              hipStream_t stream) {
    const float* x     = (const float*)d_in[0];
    const float* W_qkv = (const float*)d_in[1];
    const float* b_qkv = (const float*)d_in[2];
    const float* W_out = (const float*)d_in[3];
    const float* b_out = (const float*)d_in[4];
    const float* w3    = (const float*)d_in[5];
    const float* cb3   = (const float*)d_in[6];
    const float* w5    = (const float*)d_in[7];
    const float* cb5   = (const float*)d_in[8];
    const float* w7    = (const float*)d_in[9];
    const float* cb7   = (const float*)d_in[10];
    float* out = (float*)d_out;

    ushort_t* q = (ushort_t*)d_ws;
    ushort_t* k = q + (size_t)MROWS * DIM;
    ushort_t* v = k + (size_t)MROWS * DIM;
    float* attn    = (float*)(v + (size_t)MROWS * DIM);
    float* stat_m  = attn + (size_t)BN * NH * HD * HD;
    float* stat_is = stat_m + (size_t)BN * DIM;
    ushort_t* Wqkvt = (ushort_t*)(stat_is + (size_t)BN * DIM);
    ushort_t* Wot   = Wqkvt + (size_t)QKVD * DIM;
    ushort_t* o = k;   // alias: k dead after attn_kernel

    // d_out scratch layout: xb (bf16 x, 38.58 MB) then attn_part (37.75 MB).
    // Both dead before gemm_out_mfma writes d_out (77.17 MB total).
    ushort_t* xb = (ushort_t*)d_out;
    float* attn_part = (float*)d_out + (size_t)MROWS * DIM / 2;

    transpose_bf16_kernel<<<dim3(QKVD / 32, DIM / 32), dim3(32, 8), 0, stream>>>(
        W_qkv, Wqkvt, DIM, QKVD);
    transpose_bf16_kernel<<<dim3(DIM / 32, DIM / 32), dim3(32, 8), 0, stream>>>(
        W_out, Wot, DIM, DIM);
    {
        int n8 = MROWS * DIM / 8;
        f32_to_bf16_kernel<<<dim3((n8 + 255) / 256), 256, 0, stream>>>(x, xb, n8);
    }
    gemm_qkv_mfma<<<dim3(QKVD / 128, (MROWS + 127) / 128), 256, 0, stream>>>(
        xb, Wqkvt, b_qkv, q, k, v);
    softmax_stats_kernel<<<dim3(12, BN), dim3(64, 4), 0, stream>>>(
        (const bf16*)k, stat_m, stat_is);
    attn_kernel<<<dim3(NH, BN, NS), 256, 0, stream>>>(
        (const bf16*)k, (const bf16*)v, stat_m, attn_part);
    {
        int tot4 = BN * NH * HD * HD / 4;
        attn_reduce_kernel<<<dim3((tot4 + 255) / 256), 256, 0, stream>>>(
            attn_part, stat_is, attn);
    }
    crpe_lds_kernel<<<dim3(24, 2, BN), 256, 0, stream>>>(
        v, w3, cb3, w5, cb5, w7, cb7, o);
    combine_kernel<<<dim3(NH, 13, BN), 256, 0, stream>>>(
        q, attn, o);
    gemm_out_mfma<<<dim3(DIM / 128, (MROWS + 127) / 128), 256, 0, stream>>>(
        o, Wot, b_out, out);
}

// Round 7
// 535.984 us; speedup vs baseline: 1.2793x; 1.0527x over previous
//
#include <hip/hip_runtime.h>
#include <hip/hip_bf16.h>
#include <math.h>

#define BN    32
#define NTOK  785
#define GH    28
#define GW    28
#define DIM   768
#define QKVD  2304
#define NH    8
#define HD    96
#define MROWS (BN*NTOK)   // 25120
#define NS    4           // attn token-split
#define NPC   197         // ceil(785/4)

typedef __hip_bfloat16 bf16;
typedef unsigned short ushort_t;
typedef short s16x8 __attribute__((ext_vector_type(8)));   // 8 bf16 = 4 VGPRs
typedef float f32x4 __attribute__((ext_vector_type(4)));   // MFMA acc

// ---------------------------------------------------------------------------
// helpers
// ---------------------------------------------------------------------------
__device__ __forceinline__ void gl2lds16(const void* g, void* l) {
    // 16B per lane, LDS dest = wave-uniform base + lane*16
    __builtin_amdgcn_global_load_lds(
        (__attribute__((address_space(1))) void*)const_cast<void*>(g),
        (__attribute__((address_space(3))) void*)l, 16, 0, 0);
}

__device__ __forceinline__ ushort_t f2bf(float f) {
    bf16 h = __float2bfloat16(f);
    return *(ushort_t*)&h;
}

__device__ __forceinline__ float bf2f(ushort_t u) {
    return __bfloat162float(*(const bf16*)&u);
}

__device__ __forceinline__ s16x8 cvt8(const float* p) {   // 8 fp32 (LDS) -> bf16x8
    float4 a = *(const float4*)p;
    float4 b = *(const float4*)(p + 4);
    union { s16x8 v; __hip_bfloat162 h[4]; } r;
    r.h[0] = __float22bfloat162_rn(make_float2(a.x, a.y));
    r.h[1] = __float22bfloat162_rn(make_float2(a.z, a.w));
    r.h[2] = __float22bfloat162_rn(make_float2(b.x, b.y));
    r.h[3] = __float22bfloat162_rn(make_float2(b.z, b.w));
    return r.v;
}

// ---------------------------------------------------------------------------
// K-1: fp32 -> bf16 convert (x -> xb). 8 elems/thread, vectorized.
// ---------------------------------------------------------------------------
__global__ __launch_bounds__(256)
void f32_to_bf16_kernel(const float* __restrict__ in, ushort_t* __restrict__ out,
                        int n8) {
    int i = blockIdx.x * 256 + threadIdx.x;
    if (i >= n8) return;
    const float4* p = (const float4*)(in + (size_t)i * 8);
    float4 a = p[0], b = p[1];
    union { s16x8 v; __hip_bfloat162 h[4]; } r;
    r.h[0] = __float22bfloat162_rn(make_float2(a.x, a.y));
    r.h[1] = __float22bfloat162_rn(make_float2(a.z, a.w));
    r.h[2] = __float22bfloat162_rn(make_float2(b.x, b.y));
    r.h[3] = __float22bfloat162_rn(make_float2(b.z, b.w));
    *(s16x8*)(out + (size_t)i * 8) = r.v;
}

// ---------------------------------------------------------------------------
// K0: transpose-convert W[R][C] fp32 -> Wt[C][R] bf16
// ---------------------------------------------------------------------------
__global__ __launch_bounds__(256)
void transpose_bf16_kernel(const float* __restrict__ W, ushort_t* __restrict__ Wt,
                           int R, int C) {
    __shared__ float tile[32][33];
    int c0 = blockIdx.x * 32, r0 = blockIdx.y * 32;
    int tx = threadIdx.x, ty = threadIdx.y;   // 32 x 8
    #pragma unroll
    for (int i = 0; i < 4; ++i)
        tile[ty + i * 8][tx] = W[(size_t)(r0 + ty + i * 8) * C + c0 + tx];
    __syncthreads();
    #pragma unroll
    for (int i = 0; i < 4; ++i)
        Wt[(size_t)(c0 + ty + i * 8) * R + r0 + tx] = f2bf(tile[tx][ty + i * 8]);
}

// ---------------------------------------------------------------------------
// K1: qkv GEMM via MFMA. A = xb bf16 [M][768], Bt = W_qkv^T bf16 [2304][768].
// 128x128 tile, BK=64 (halves barrier-drain count vs BK=32), 4 waves.
// LDS rows are 128 B = 8 x 16B slots, XOR-swizzled BOTH-sides (rule #21):
//   staging src slot = (lane&7)^(lane>>3)  [linear LDS dest via global_load_lds]
//   read slot        = (kh*4+q4)^(l15&7)
// This slot pattern is correctness-proven by the r4/r5 256^2 kernels.
// ---------------------------------------------------------------------------
__global__ __launch_bounds__(256)
void gemm_qkv_mfma(const ushort_t* __restrict__ A, const ushort_t* __restrict__ Bt,
                   const float* __restrict__ bias,
                   ushort_t* __restrict__ q, ushort_t* __restrict__ kk,
                   ushort_t* __restrict__ v) {
    const int M = MROWS, K = DIM;
    __shared__ ushort_t Asm[128 * 64];   // 16 KB
    __shared__ ushort_t Bsm[128 * 64];   // 16 KB
    const int tid  = threadIdx.x;
    const int wave = tid >> 6;
    const int lane = tid & 63;
    const int row0 = blockIdx.y * 128;
    const int col0 = blockIdx.x * 128;
    const int wm = wave >> 1, wn = wave & 1;
    const int q4 = lane >> 4, l15 = lane & 15;
    const int l8 = lane >> 3;                    // 0..7
    const int sg = ((lane & 7) ^ l8) * 8;        // pre-swizzled global src slot

    f32x4 acc[4][4];
    #pragma unroll
    for (int i = 0; i < 4; ++i)
        #pragma unroll
        for (int j = 0; j < 4; ++j) acc[i][j] = (f32x4){0.f, 0.f, 0.f, 0.f};

    for (int kt = 0; kt < K; kt += 64) {
        #pragma unroll
        for (int rr = 0; rr < 4; ++rr) {
            int lrow = wave * 32 + rr * 8;
            int grow = min(row0 + lrow + l8, M - 1);
            gl2lds16(A + (size_t)grow * K + kt + sg, &Asm[lrow * 64]);
        }
        #pragma unroll
        for (int rr = 0; rr < 4; ++rr) {
            int lrow = wave * 32 + rr * 8;
            gl2lds16(Bt + (size_t)(col0 + lrow + l8) * K + kt + sg,
                     &Bsm[lrow * 64]);
        }
        __syncthreads();
        #pragma unroll
        for (int kh = 0; kh < 2; ++kh) {
            const int sl = ((kh * 4 + q4) ^ (l15 & 7)) * 8;
            s16x8 af[4], bfr[4];
            #pragma unroll
            for (int mi = 0; mi < 4; ++mi)
                af[mi] = *(const s16x8*)&Asm[(wm * 64 + mi * 16 + l15) * 64 + sl];
            #pragma unroll
            for (int ni = 0; ni < 4; ++ni)
                bfr[ni] = *(const s16x8*)&Bsm[(wn * 64 + ni * 16 + l15) * 64 + sl];
            #pragma unroll
            for (int mi = 0; mi < 4; ++mi)
                #pragma unroll
                for (int ni = 0; ni < 4; ++ni)
                    acc[mi][ni] = __builtin_amdgcn_mfma_f32_16x16x32_bf16(
                        af[mi], bfr[ni], acc[mi][ni], 0, 0, 0);
        }
        __syncthreads();
    }
    int colbase = col0 + wn * 64;
    int seg = colbase / DIM;
    int csub = colbase - seg * DIM;
    ushort_t* outp = (seg == 0) ? q : (seg == 1) ? kk : v;
    #pragma unroll
    for (int mi = 0; mi < 4; ++mi) {
        #pragma unroll
        for (int ni = 0; ni < 4; ++ni) {
            int gcol = colbase + ni * 16 + l15;
            int col  = csub + ni * 16 + l15;
            float bb = bias[gcol];
            #pragma unroll
            for (int j = 0; j < 4; ++j) {
                int row = row0 + wm * 64 + mi * 16 + q4 * 4 + j;
                if (row < M)
                    outp[(size_t)row * DIM + col] = f2bf(acc[mi][ni][j] + bb);
            }
        }
    }
}

// ---------------------------------------------------------------------------
// K6: out GEMM via MFMA. A = o bf16, Bt = W_out^T bf16, C fp32.
// Same BK=64 swizzled structure as K1.
// ---------------------------------------------------------------------------
__global__ __launch_bounds__(256)
void gemm_out_mfma(const ushort_t* __restrict__ A, const ushort_t* __restrict__ Bt,
                   const float* __restrict__ bias, float* __restrict__ C) {
    const int M = MROWS, N = DIM, K = DIM;
    __shared__ ushort_t Asm[128 * 64];
    __shared__ ushort_t Bsm[128 * 64];
    const int tid  = threadIdx.x;
    const int wave = tid >> 6;
    const int lane = tid & 63;
    const int row0 = blockIdx.y * 128;
    const int col0 = blockIdx.x * 128;
    const int wm = wave >> 1, wn = wave & 1;
    const int q4 = lane >> 4, l15 = lane & 15;
    const int l8 = lane >> 3;
    const int sg = ((lane & 7) ^ l8) * 8;

    f32x4 acc[4][4];
    #pragma unroll
    for (int i = 0; i < 4; ++i)
        #pragma unroll
        for (int j = 0; j < 4; ++j) acc[i][j] = (f32x4){0.f, 0.f, 0.f, 0.f};

    for (int kt = 0; kt < K; kt += 64) {
        #pragma unroll
        for (int rr = 0; rr < 4; ++rr) {
            int lrow = wave * 32 + rr * 8;
            int grow = min(row0 + lrow + l8, M - 1);
            gl2lds16(A + (size_t)grow * K + kt + sg, &Asm[lrow * 64]);
        }
        #pragma unroll
        for (int rr = 0; rr < 4; ++rr) {
            int lrow = wave * 32 + rr * 8;
            gl2lds16(Bt + (size_t)(col0 + lrow + l8) * K + kt + sg,
                     &Bsm[lrow * 64]);
        }
        __syncthreads();
        #pragma unroll
        for (int kh = 0; kh < 2; ++kh) {
            const int sl = ((kh * 4 + q4) ^ (l15 & 7)) * 8;
            s16x8 af[4], bfr[4];
            #pragma unroll
            for (int mi = 0; mi < 4; ++mi)
                af[mi] = *(const s16x8*)&Asm[(wm * 64 + mi * 16 + l15) * 64 + sl];
            #pragma unroll
            for (int ni = 0; ni < 4; ++ni)
                bfr[ni] = *(const s16x8*)&Bsm[(wn * 64 + ni * 16 + l15) * 64 + sl];
            #pragma unroll
            for (int mi = 0; mi < 4; ++mi)
                #pragma unroll
                for (int ni = 0; ni < 4; ++ni)
                    acc[mi][ni] = __builtin_amdgcn_mfma_f32_16x16x32_bf16(
                        af[mi], bfr[ni], acc[mi][ni], 0, 0, 0);
        }
        __syncthreads();
    }
    #pragma unroll
    for (int mi = 0; mi < 4; ++mi) {
        #pragma unroll
        for (int ni = 0; ni < 4; ++ni) {
            int col = col0 + wn * 64 + ni * 16 + l15;
            float bb = bias[col];
            #pragma unroll
            for (int j = 0; j < 4; ++j) {
                int row = row0 + wm * 64 + mi * 16 + q4 * 4 + j;
                if (row < M)
                    C[(size_t)row * N + col] = acc[mi][ni][j] + bb;
            }
        }
    }
}

// ---------------------------------------------------------------------------
// K2: per-(b,c) softmax stats over 785 tokens of k. Vectorized rewrite:
// 256 thr = 8 ch-chunks (s16x8) x 32 token-groups; two-pass (max, then
// single-exp sum); LDS reduce across token-groups. 16B/lane loads (G13).
// ---------------------------------------------------------------------------
__global__ __launch_bounds__(256)
void softmax_stats_kernel(const ushort_t* __restrict__ k,
                          float* __restrict__ stat_m, float* __restrict__ stat_is) {
    const int b  = blockIdx.y;
    const int c0 = blockIdx.x * 64;
    const int tid = threadIdx.x;
    const int c8 = tid & 7, tg = tid >> 3;   // chunk 0..7, token-group 0..31
    __shared__ float red[32][64];
    __shared__ float smB[64];
    const ushort_t* base = k + (size_t)b * NTOK * DIM + c0 + c8 * 8;

    float mx[8];
    #pragma unroll
    for (int j = 0; j < 8; ++j) mx[j] = -1e30f;
    for (int n = tg; n < NTOK; n += 32) {
        union { s16x8 v; ushort_t u[8]; } kv;
        kv.v = *(const s16x8*)(base + (size_t)n * DIM);
        #pragma unroll
        for (int j = 0; j < 8; ++j) mx[j] = fmaxf(mx[j], bf2f(kv.u[j]));
    }
    #pragma unroll
    for (int j = 0; j < 8; ++j) red[tg][c8 * 8 + j] = mx[j];
    __syncthreads();
    if (tid < 64) {
        float M = red[0][tid];
        #pragma unroll
        for (int i = 1; i < 32; ++i) M = fmaxf(M, red[i][tid]);
        smB[tid] = M;
    }
    __syncthreads();

    float sm8[8], ss[8];
    #pragma unroll
    for (int j = 0; j < 8; ++j) { sm8[j] = smB[c8 * 8 + j]; ss[j] = 0.f; }
    for (int n = tg; n < NTOK; n += 32) {
        union { s16x8 v; ushort_t u[8]; } kv;
        kv.v = *(const s16x8*)(base + (size_t)n * DIM);
        #pragma unroll
        for (int j = 0; j < 8; ++j) ss[j] += __expf(bf2f(kv.u[j]) - sm8[j]);
    }
    __syncthreads();
    #pragma unroll
    for (int j = 0; j < 8; ++j) red[tg][c8 * 8 + j] = ss[j];
    __syncthreads();
    if (tid < 64) {
        float S = 0.f;
        #pragma unroll
        for (int i = 0; i < 32; ++i) S += red[i][tid];
        stat_m[b * DIM + c0 + tid]  = smB[tid];
        stat_is[b * DIM + c0 + tid] = 1.f / S;
    }
}

// ---------------------------------------------------------------------------
// K3: attn_part[ns][b,h,d,e] = sum_{n in chunk} exp(k[n,d]-m_d) * v[n,e]
// MFMA version (r6, verified). C = Ek^T * V, operands staged transposed f32,
// cvt8 on fragment read. 4 waves = 2x2 quadrants of 48x48.
// ---------------------------------------------------------------------------
__global__ __launch_bounds__(256)
void attn_kernel(const bf16* __restrict__ k, const bf16* __restrict__ v,
                 const float* __restrict__ stat_m,
                 float* __restrict__ attn_part) {
    const int h = blockIdx.x, b = blockIdx.y, ns = blockIdx.z;
    const int t = threadIdx.x;
    const int wave = t >> 6, lane = t & 63;
    const int q4 = lane >> 4, l15 = lane & 15;
    const int wd = wave >> 1, we = wave & 1;   // quadrant: d-half, e-half
    __shared__ float ekT[96][36];
    __shared__ float vT[96][36];
    __shared__ float smM[96];
    if (t < 96) smM[t] = stat_m[b * DIM + h * HD + t];
    __syncthreads();

    f32x4 acc[3][3];
    #pragma unroll
    for (int i = 0; i < 3; ++i)
        #pragma unroll
        for (int j = 0; j < 3; ++j) acc[i][j] = (f32x4){0.f, 0.f, 0.f, 0.f};

    const bf16* kbase = k + (size_t)b * NTOK * DIM + h * HD;
    const bf16* vbase = v + (size_t)b * NTOK * DIM + h * HD;
    const int nlo = ns * NPC;
    const int nhi = min(NTOK, nlo + NPC);
    const int tl = t >> 3;          // token slot 0..31
    const int cg = (t & 7) * 12;    // channel base 0,12,..,84
    for (int n0 = nlo; n0 < nhi; n0 += 32) {
        const int n = n0 + tl;
        if (n < nhi) {
            #pragma unroll
            for (int j = 0; j < 6; ++j) {
                float2 kf = __bfloat1622float2(
                    *(const __hip_bfloat162*)&kbase[(size_t)n * DIM + cg + 2 * j]);
                float2 vf = __bfloat1622float2(
                    *(const __hip_bfloat162*)&vbase[(size_t)n * DIM + cg + 2 * j]);
                ekT[cg + 2 * j][tl]     = __expf(kf.x - smM[cg + 2 * j]);
                ekT[cg + 2 * j + 1][tl] = __expf(kf.y - smM[cg + 2 * j + 1]);
                vT[cg + 2 * j][tl]      = vf.x;
                vT[cg + 2 * j + 1][tl]  = vf.y;
            }
        } else {
            #pragma unroll
            for (int j = 0; j < 12; ++j) {
                ekT[cg + j][tl] = 0.f;
                vT[cg + j][tl]  = 0.f;
            }
        }
        __syncthreads();
        s16x8 af[3], bfr[3];
        #pragma unroll
        for (int i = 0; i < 3; ++i)
            af[i] = cvt8(&ekT[wd * 48 + i * 16 + l15][q4 * 8]);
        #pragma unroll
        for (int i = 0; i < 3; ++i)
            bfr[i] = cvt8(&vT[we * 48 + i * 16 + l15][q4 * 8]);
        #pragma unroll
        for (int i = 0; i < 3; ++i)
            #pragma unroll
            for (int j = 0; j < 3; ++j)
                acc[i][j] = __builtin_amdgcn_mfma_f32_16x16x32_bf16(
                    af[i], bfr[j], acc[i][j], 0, 0, 0);
        __syncthreads();
    }
    float* abase = attn_part + (size_t)ns * BN * NH * HD * HD
                 + (size_t)(b * NH + h) * HD * HD;
    #pragma unroll
    for (int i = 0; i < 3; ++i)
        #pragma unroll
        for (int j = 0; j < 3; ++j)
            #pragma unroll
            for (int r = 0; r < 4; ++r)
                abase[(size_t)(wd * 48 + i * 16 + q4 * 4 + r) * HD
                      + we * 48 + j * 16 + l15] = acc[i][j][r];
}

// ---------------------------------------------------------------------------
// K3b: attn[b,h,d,e] = stat_is[b,h*96+d] * sum_s attn_part[s][b,h,d,e]
// ---------------------------------------------------------------------------
__global__ __launch_bounds__(256)
void attn_reduce_kernel(const float* __restrict__ part,
                        const float* __restrict__ stat_is,
                        float* __restrict__ attn) {
    const int TOT4 = BN * NH * HD * HD / 4;   // 589824
    int i = blockIdx.x * 256 + threadIdx.x;
    if (i >= TOT4) return;
    size_t base = (size_t)i * 4;
    int bh = (int)(base / (HD * HD));
    int d  = (int)((base / HD) % HD);
    float is = stat_is[(bh >> 3) * DIM + (bh & 7) * HD + d];
    const size_t PSZ = (size_t)BN * NH * HD * HD;
    float4 s = *(const float4*)&part[base];
    float4 p1 = *(const float4*)&part[PSZ + base];
    float4 p2 = *(const float4*)&part[2 * PSZ + base];
    float4 p3 = *(const float4*)&part[3 * PSZ + base];
    s.x = (s.x + p1.x + p2.x + p3.x) * is;
    s.y = (s.y + p1.y + p2.y + p3.y) * is;
    s.z = (s.z + p1.z + p2.z + p3.z) * is;
    s.w = (s.w + p1.w + p2.w + p3.w) * is;
    *(float4*)&attn[base] = s;
}

// ---------------------------------------------------------------------------
// K4: CRPE depthwise conv, restructured for occupancy + branch-free taps.
// ---------------------------------------------------------------------------
#define CRS 1104   // conv tile row stride in bf16 elems (34*32 + 16 pad)

template<int KS>
__device__ __forceinline__ void crpe_conv32(const ushort_t* __restrict__ vimg,
                                            const float* __restrict__ wsm,
                                            float b0, float b1,
                                            ushort_t* __restrict__ ob,
                                            int p, int yl, int y) {
    constexpr int R = KS / 2;
    const float* wA = wsm + (2 * p) * KS * KS;
    const float* wB = wA + KS * KS;
    #pragma unroll
    for (int xo = 0; xo < 28; xo += 7) {
        float a0[7], a1[7];
        #pragma unroll
        for (int u = 0; u < 7; ++u) { a0[u] = b0; a1[u] = b1; }
        #pragma unroll
        for (int ky = 0; ky < KS; ++ky) {
            const ushort_t* rp = vimg + (yl + ky - R + 3) * CRS
                                      + (xo - R + 3) * 32 + 2 * p;
            float2 seg[6 + KS];
            #pragma unroll
            for (int i = 0; i < 6 + KS; ++i)
                seg[i] = __bfloat1622float2(*(const __hip_bfloat162*)(rp + i * 32));
            #pragma unroll
            for (int kx = 0; kx < KS; ++kx) {
                float wa = wA[ky * KS + kx];
                float wb = wB[ky * KS + kx];
                #pragma unroll
                for (int u = 0; u < 7; ++u) {
                    a0[u] = fmaf(wa, seg[u + kx].x, a0[u]);
                    a1[u] = fmaf(wb, seg[u + kx].y, a1[u]);
                }
            }
        }
        #pragma unroll
        for (int u = 0; u < 7; ++u)
            *(__hip_bfloat162*)&ob[(size_t)(1 + y * GW + xo + u) * DIM + 2 * p] =
                __float22bfloat162_rn(make_float2(a0[u], a1[u]));
    }
}

__global__ __launch_bounds__(256)
void crpe_lds_kernel(const ushort_t* __restrict__ v,
                     const float* __restrict__ w3, const float* __restrict__ b3,
                     const float* __restrict__ w5, const float* __restrict__ b5,
                     const float* __restrict__ w7, const float* __restrict__ b7,
                     ushort_t* __restrict__ o) {
    __shared__ ushort_t vimg[20 * CRS];   // 44,160 B
    __shared__ float    wsm[32 * 49];     //  6,272 B
    const int cg  = blockIdx.x;    // 0..23, 32-channel group
    const int hf  = blockIdx.y;    // 0..1 image half (rows 0..13 / 14..27)
    const int b   = blockIdx.z;
    const int tid = threadIdx.x;
    const int c0  = cg * 32;

    const float* wsrc; const float* bsrc; int ks;
    if (c0 < 192)      { wsrc = w3 + c0 * 9;          bsrc = b3 + c0;         ks = 3; }
    else if (c0 < 480) { wsrc = w5 + (c0 - 192) * 25; bsrc = b5 + (c0 - 192); ks = 5; }
    else               { wsrc = w7 + (c0 - 480) * 49; bsrc = b7 + (c0 - 480); ks = 7; }
    const int ksq = ks * ks;

    const int zr0 = hf ? 17 : 0;
    for (int idx = tid; idx < 3 * 138; idx += 256) {
        int rr = idx / 138, cc = idx - rr * 138;
        *(s16x8*)&vimg[(zr0 + rr) * CRS + cc * 8] = (s16x8){0,0,0,0,0,0,0,0};
    }
    for (int idx = tid; idx < 17 * 24; idx += 256) {
        int vr = idx / 24, cc = idx - vr * 24;
        int ly = hf ? vr : vr + 3;
        int ch = (cc < 12) ? cc : (112 + cc);
        *(s16x8*)&vimg[ly * CRS + ch * 8] = (s16x8){0,0,0,0,0,0,0,0};
    }
    for (int idx = tid; idx < 32 * ksq; idx += 256)
        wsm[idx] = wsrc[idx];
    const ushort_t* vb = v + (size_t)b * NTOK * DIM + c0;
    const int gy0 = hf ? 11 : 0;
    for (int idx = tid; idx < 17 * 28 * 4; idx += 256) {
        int vr = idx / 112, rem = idx - vr * 112;
        int px = rem >> 2, c8 = rem & 3;
        int gy = gy0 + vr;
        int ly = hf ? vr : vr + 3;
        *(s16x8*)&vimg[ly * CRS + (px + 3) * 32 + c8 * 8] =
            *(const s16x8*)(vb + (size_t)(1 + gy * GW + px) * DIM + c8 * 8);
    }
    ushort_t* ob = o + (size_t)b * NTOK * DIM + c0;
    if (hf == 0 && tid < 32) ob[tid] = 0;   // CLS row: rp = 0
    __syncthreads();

    const int p  = tid & 15;       // channel pair 0..15
    const int yl = tid >> 4;       // row within half 0..15
    if (yl >= 14) return;
    const int y = hf * 14 + yl;    // global row
    float bb0 = bsrc[2 * p], bb1 = bsrc[2 * p + 1];
    if (ks == 3)      crpe_conv32<3>(vimg, wsm, bb0, bb1, ob, p, yl, y);
    else if (ks == 5) crpe_conv32<5>(vimg, wsm, bb0, bb1, ob, p, yl, y);
    else              crpe_conv32<7>(vimg, wsm, bb0, bb1, ob, p, yl, y);
}

// ---------------------------------------------------------------------------
// K5: o[b,n,h*96+e] = scale * sum_d q[n,d] attn[d,e] + q[n,e] * rp (in-place)
// MFMA version (r6, verified).
// ---------------------------------------------------------------------------
__global__ __launch_bounds__(256)
void combine_kernel(const ushort_t* __restrict__ q, const float* __restrict__ attn,
                    ushort_t* __restrict__ o) {
    const int h = blockIdx.x, b = blockIdx.z;
    const int n0 = blockIdx.y * 64;
    const int t = threadIdx.x;
    const int wave = t >> 6, lane = t & 63;
    const int q4 = lane >> 4, l15 = lane & 15;
    __shared__ ushort_t qs[64][104];
    __shared__ ushort_t atT[96][104];

    const ushort_t* qbase = q + (size_t)b * NTOK * DIM + h * HD;
    #pragma unroll
    for (int i = 0; i < 3; ++i) {
        int idx = t + i * 256;          // 0..767 = 64 rows x 12 chunks
        int rr = idx / 12, c8 = idx % 12;
        int n = n0 + rr;
        s16x8 val = (s16x8){0,0,0,0,0,0,0,0};
        if (n < NTOK) val = *(const s16x8*)(qbase + (size_t)n * DIM + c8 * 8);
        *(s16x8*)&qs[rr][c8 * 8] = val;
    }
    const float* abase = attn + (size_t)(b * NH + h) * HD * HD;
    #pragma unroll
    for (int i = 0; i < 36; ++i) {
        int idx = t + i * 256;          // 0..9215; read coalesced [d][e]
        int d = idx / 96, e = idx % 96;
        atT[e][d] = f2bf(abase[idx]);
    }
    __syncthreads();

    f32x4 acc[6];
    #pragma unroll
    for (int i = 0; i < 6; ++i) acc[i] = (f32x4){0.f, 0.f, 0.f, 0.f};
    #pragma unroll
    for (int ks = 0; ks < 3; ++ks) {
        s16x8 aq = *(const s16x8*)&qs[wave * 16 + l15][ks * 32 + q4 * 8];
        #pragma unroll
        for (int et = 0; et < 6; ++et) {
            s16x8 bfrg = *(const s16x8*)&atT[et * 16 + l15][ks * 32 + q4 * 8];
            acc[et] = __builtin_amdgcn_mfma_f32_16x16x32_bf16(
                aq, bfrg, acc[et], 0, 0, 0);
        }
    }

    const float scale = 0.10206207261596575f;  // 96^-0.5
    ushort_t* obase = o + (size_t)b * NTOK * DIM + h * HD;
    #pragma unroll
    for (int et = 0; et < 6; ++et) {
        int e = et * 16 + l15;
        #pragma unroll
        for (int r = 0; r < 4; ++r) {
            int rr = wave * 16 + q4 * 4 + r;
            int n = n0 + rr;
            if (n >= NTOK) continue;
            size_t oa = (size_t)n * DIM + e;
            float rp = __bfloat162float(*(const bf16*)&obase[oa]);
            float qv = __bfloat162float(*(const bf16*)&qs[rr][e]);
            obase[oa] = f2bf(scale * acc[et][r] + qv * rp);
        }
    }
}

// ---------------------------------------------------------------------------
extern "C" void kernel_launch(void* const* d_in, const int* in_sizes, int n_in,
                              void* d_out, int out_size, void* d_ws, size_t ws_size,
                              hipStream_t stream) {
    const float* x     = (const float*)d_in[0];
    const float* W_qkv = (const float*)d_in[1];
    const float* b_qkv = (const float*)d_in[2];
    const float* W_out = (const float*)d_in[3];
    const float* b_out = (const float*)d_in[4];
    const float* w3    = (const float*)d_in[5];
    const float* cb3   = (const float*)d_in[6];
    const float* w5    = (const float*)d_in[7];
    const float* cb5   = (const float*)d_in[8];
    const float* w7    = (const float*)d_in[9];
    const float* cb7   = (const float*)d_in[10];
    float* out = (float*)d_out;

    ushort_t* q = (ushort_t*)d_ws;
    ushort_t* k = q + (size_t)MROWS * DIM;
    ushort_t* v = k + (size_t)MROWS * DIM;
    float* attn    = (float*)(v + (size_t)MROWS * DIM);
    float* stat_m  = attn + (size_t)BN * NH * HD * HD;
    float* stat_is = stat_m + (size_t)BN * DIM;
    ushort_t* Wqkvt = (ushort_t*)(stat_is + (size_t)BN * DIM);
    ushort_t* Wot   = Wqkvt + (size_t)QKVD * DIM;
    ushort_t* o = k;   // alias: k dead after attn_kernel

    // d_out scratch layout: xb (bf16 x, 38.58 MB) then attn_part (37.75 MB).
    // Both dead before gemm_out_mfma writes d_out (77.17 MB total).
    ushort_t* xb = (ushort_t*)d_out;
    float* attn_part = (float*)d_out + (size_t)MROWS * DIM / 2;

    transpose_bf16_kernel<<<dim3(QKVD / 32, DIM / 32), dim3(32, 8), 0, stream>>>(
        W_qkv, Wqkvt, DIM, QKVD);
    transpose_bf16_kernel<<<dim3(DIM / 32, DIM / 32), dim3(32, 8), 0, stream>>>(
        W_out, Wot, DIM, DIM);
    {
        int n8 = MROWS * DIM / 8;
        f32_to_bf16_kernel<<<dim3((n8 + 255) / 256), 256, 0, stream>>>(x, xb, n8);
    }
    gemm_qkv_mfma<<<dim3(QKVD / 128, (MROWS + 127) / 128), 256, 0, stream>>>(
        xb, Wqkvt, b_qkv, q, k, v);
    softmax_stats_kernel<<<dim3(12, BN), 256, 0, stream>>>(
        k, stat_m, stat_is);
    attn_kernel<<<dim3(NH, BN, NS), 256, 0, stream>>>(
        (const bf16*)k, (const bf16*)v, stat_m, attn_part);
    {
        int tot4 = BN * NH * HD * HD / 4;
        attn_reduce_kernel<<<dim3((tot4 + 255) / 256), 256, 0, stream>>>(
            attn_part, stat_is, attn);
    }
    crpe_lds_kernel<<<dim3(24, 2, BN), 256, 0, stream>>>(
        v, w3, cb3, w5, cb5, w7, cb7, o);
    combine_kernel<<<dim3(NH, 13, BN), 256, 0, stream>>>(
        q, attn, o);
    gemm_out_mfma<<<dim3(DIM / 128, (MROWS + 127) / 128), 256, 0, stream>>>(
        o, Wot, b_out, out);
}

// Round 8
// 503.114 us; speedup vs baseline: 1.3628x; 1.0653x over previous
//
#include <hip/hip_runtime.h>
#include <hip/hip_bf16.h>
#include <math.h>

#define BN    32
#define NTOK  785
#define GH    28
#define GW    28
#define DIM   768
#define QKVD  2304
#define NH    8
#define HD    96
#define MROWS (BN*NTOK)   // 25120
#define NS    4           // attn token-split
#define NPC   197         // ceil(785/4)

typedef __hip_bfloat16 bf16;
typedef unsigned short ushort_t;
typedef short s16x8 __attribute__((ext_vector_type(8)));   // 8 bf16 = 4 VGPRs
typedef float f32x4 __attribute__((ext_vector_type(4)));   // MFMA acc

// ---------------------------------------------------------------------------
// helpers
// ---------------------------------------------------------------------------
__device__ __forceinline__ void gl2lds16(const void* g, void* l) {
    // 16B per lane, LDS dest = wave-uniform base + lane*16
    __builtin_amdgcn_global_load_lds(
        (__attribute__((address_space(1))) void*)const_cast<void*>(g),
        (__attribute__((address_space(3))) void*)l, 16, 0, 0);
}

__device__ __forceinline__ ushort_t f2bf(float f) {
    bf16 h = __float2bfloat16(f);
    return *(ushort_t*)&h;
}

__device__ __forceinline__ float bf2f(ushort_t u) {
    return __bfloat162float(*(const bf16*)&u);
}

__device__ __forceinline__ s16x8 cvt8(const float* p) {   // 8 fp32 (LDS) -> bf16x8
    float4 a = *(const float4*)p;
    float4 b = *(const float4*)(p + 4);
    union { s16x8 v; __hip_bfloat162 h[4]; } r;
    r.h[0] = __float22bfloat162_rn(make_float2(a.x, a.y));
    r.h[1] = __float22bfloat162_rn(make_float2(a.z, a.w));
    r.h[2] = __float22bfloat162_rn(make_float2(b.x, b.y));
    r.h[3] = __float22bfloat162_rn(make_float2(b.z, b.w));
    return r.v;
}

// bijective XCD swizzle (m204): contiguous tile chunks per XCD. Works for
// any nwg (3546, 1182 here: both %8 != 0 -> must use bijective form).
__device__ __forceinline__ int xcd_swizzle(int orig, int nwg) {
    int qd = nwg >> 3, r8 = nwg & 7;
    int xcd = orig & 7, idx = orig >> 3;
    return (xcd < r8 ? xcd * (qd + 1) : r8 * (qd + 1) + (xcd - r8) * qd) + idx;
}

// ---------------------------------------------------------------------------
// K-1: fp32 -> bf16 convert (x -> xb). 8 elems/thread, vectorized.
// ---------------------------------------------------------------------------
__global__ __launch_bounds__(256)
void f32_to_bf16_kernel(const float* __restrict__ in, ushort_t* __restrict__ out,
                        int n8) {
    int i = blockIdx.x * 256 + threadIdx.x;
    if (i >= n8) return;
    const float4* p = (const float4*)(in + (size_t)i * 8);
    float4 a = p[0], b = p[1];
    union { s16x8 v; __hip_bfloat162 h[4]; } r;
    r.h[0] = __float22bfloat162_rn(make_float2(a.x, a.y));
    r.h[1] = __float22bfloat162_rn(make_float2(a.z, a.w));
    r.h[2] = __float22bfloat162_rn(make_float2(b.x, b.y));
    r.h[3] = __float22bfloat162_rn(make_float2(b.z, b.w));
    *(s16x8*)(out + (size_t)i * 8) = r.v;
}

// ---------------------------------------------------------------------------
// K0: transpose-convert W[R][C] fp32 -> Wt[C][R] bf16
// ---------------------------------------------------------------------------
__global__ __launch_bounds__(256)
void transpose_bf16_kernel(const float* __restrict__ W, ushort_t* __restrict__ Wt,
                           int R, int C) {
    __shared__ float tile[32][33];
    int c0 = blockIdx.x * 32, r0 = blockIdx.y * 32;
    int tx = threadIdx.x, ty = threadIdx.y;   // 32 x 8
    #pragma unroll
    for (int i = 0; i < 4; ++i)
        tile[ty + i * 8][tx] = W[(size_t)(r0 + ty + i * 8) * C + c0 + tx];
    __syncthreads();
    #pragma unroll
    for (int i = 0; i < 4; ++i)
        Wt[(size_t)(c0 + ty + i * 8) * R + r0 + tx] = f2bf(tile[tx][ty + i * 8]);
}

// ---------------------------------------------------------------------------
// K1: qkv GEMM via MFMA (PROVEN BK=32 shape, r3/r6: 148 us) + XCD swizzle.
// A = xb bf16 [M][768], Bt = W_qkv^T bf16 [2304][768]. 128x128 tile, 4 waves.
// XOR-swizzled LDS both-sides (rule #21).
// ---------------------------------------------------------------------------
__global__ __launch_bounds__(256)
void gemm_qkv_mfma(const ushort_t* __restrict__ A, const ushort_t* __restrict__ Bt,
                   const float* __restrict__ bias,
                   ushort_t* __restrict__ q, ushort_t* __restrict__ kk,
                   ushort_t* __restrict__ v) {
    const int M = MROWS, K = DIM;
    __shared__ ushort_t Asm[128 * 32];   // 8 KB
    __shared__ ushort_t Bsm[128 * 32];   // 8 KB
    const int tid  = threadIdx.x;
    const int wave = tid >> 6;
    const int lane = tid & 63;
    const int nwg  = gridDim.x * gridDim.y;
    const int swb  = xcd_swizzle(blockIdx.y * gridDim.x + blockIdx.x, nwg);
    const int row0 = (swb / gridDim.x) * 128;
    const int col0 = (swb % gridDim.x) * 128;
    const int wm = wave >> 1, wn = wave & 1;
    const int q4 = lane >> 4, l15 = lane & 15;
    const int slotg = (lane & 3) ^ ((lane >> 3) & 3);  // staging source slot
    const int swz   = (l15 >> 1) & 3;                  // read-side row xor

    f32x4 acc[4][4];
    #pragma unroll
    for (int i = 0; i < 4; ++i)
        #pragma unroll
        for (int j = 0; j < 4; ++j) acc[i][j] = (f32x4){0.f, 0.f, 0.f, 0.f};

    for (int kt = 0; kt < K; kt += 32) {
        #pragma unroll
        for (int r = 0; r < 2; ++r) {
            int seg = r * 4 + wave;
            int rit = seg * 16 + (lane >> 2);
            int grow = min(row0 + rit, M - 1);
            const ushort_t* gp = A + (size_t)grow * K + kt + slotg * 8;
            gl2lds16(gp, &Asm[seg * 512]);
        }
        #pragma unroll
        for (int r = 0; r < 2; ++r) {
            int seg = r * 4 + wave;
            int nit = seg * 16 + (lane >> 2);
            const ushort_t* gp = Bt + (size_t)(col0 + nit) * K + kt + slotg * 8;
            gl2lds16(gp, &Bsm[seg * 512]);
        }
        __syncthreads();
        s16x8 af[4], bfr[4];
        #pragma unroll
        for (int mi = 0; mi < 4; ++mi)
            af[mi] = *(const s16x8*)&Asm[(wm * 64 + mi * 16 + l15) * 32
                                         + ((q4 ^ swz) * 8)];
        #pragma unroll
        for (int ni = 0; ni < 4; ++ni)
            bfr[ni] = *(const s16x8*)&Bsm[(wn * 64 + ni * 16 + l15) * 32
                                          + ((q4 ^ swz) * 8)];
        #pragma unroll
        for (int mi = 0; mi < 4; ++mi)
            #pragma unroll
            for (int ni = 0; ni < 4; ++ni)
                acc[mi][ni] = __builtin_amdgcn_mfma_f32_16x16x32_bf16(
                    af[mi], bfr[ni], acc[mi][ni], 0, 0, 0);
        __syncthreads();
    }
    int colbase = col0 + wn * 64;
    int seg = colbase / DIM;
    int csub = colbase - seg * DIM;
    ushort_t* outp = (seg == 0) ? q : (seg == 1) ? kk : v;
    #pragma unroll
    for (int mi = 0; mi < 4; ++mi) {
        #pragma unroll
        for (int ni = 0; ni < 4; ++ni) {
            int gcol = colbase + ni * 16 + l15;
            int col  = csub + ni * 16 + l15;
            float bb = bias[gcol];
            #pragma unroll
            for (int j = 0; j < 4; ++j) {
                int row = row0 + wm * 64 + mi * 16 + q4 * 4 + j;
                if (row < M)
                    outp[(size_t)row * DIM + col] = f2bf(acc[mi][ni][j] + bb);
            }
        }
    }
}

// ---------------------------------------------------------------------------
// K6: out GEMM via MFMA (BK=32 proven shape) + XCD swizzle.
// ---------------------------------------------------------------------------
__global__ __launch_bounds__(256)
void gemm_out_mfma(const ushort_t* __restrict__ A, const ushort_t* __restrict__ Bt,
                   const float* __restrict__ bias, float* __restrict__ C) {
    const int M = MROWS, N = DIM, K = DIM;
    __shared__ ushort_t Asm[128 * 32];
    __shared__ ushort_t Bsm[128 * 32];
    const int tid  = threadIdx.x;
    const int wave = tid >> 6;
    const int lane = tid & 63;
    const int nwg  = gridDim.x * gridDim.y;
    const int swb  = xcd_swizzle(blockIdx.y * gridDim.x + blockIdx.x, nwg);
    const int row0 = (swb / gridDim.x) * 128;
    const int col0 = (swb % gridDim.x) * 128;
    const int wm = wave >> 1, wn = wave & 1;
    const int q4 = lane >> 4, l15 = lane & 15;
    const int slotg = (lane & 3) ^ ((lane >> 3) & 3);
    const int swz   = (l15 >> 1) & 3;

    f32x4 acc[4][4];
    #pragma unroll
    for (int i = 0; i < 4; ++i)
        #pragma unroll
        for (int j = 0; j < 4; ++j) acc[i][j] = (f32x4){0.f, 0.f, 0.f, 0.f};

    for (int kt = 0; kt < K; kt += 32) {
        #pragma unroll
        for (int r = 0; r < 2; ++r) {
            int seg = r * 4 + wave;
            int rit = seg * 16 + (lane >> 2);
            int grow = min(row0 + rit, M - 1);
            const ushort_t* gp = A + (size_t)grow * K + kt + slotg * 8;
            gl2lds16(gp, &Asm[seg * 512]);
        }
        #pragma unroll
        for (int r = 0; r < 2; ++r) {
            int seg = r * 4 + wave;
            int nit = seg * 16 + (lane >> 2);
            const ushort_t* gp = Bt + (size_t)(col0 + nit) * K + kt + slotg * 8;
            gl2lds16(gp, &Bsm[seg * 512]);
        }
        __syncthreads();
        s16x8 af[4], bfr[4];
        #pragma unroll
        for (int mi = 0; mi < 4; ++mi)
            af[mi] = *(const s16x8*)&Asm[(wm * 64 + mi * 16 + l15) * 32
                                         + ((q4 ^ swz) * 8)];
        #pragma unroll
        for (int ni = 0; ni < 4; ++ni)
            bfr[ni] = *(const s16x8*)&Bsm[(wn * 64 + ni * 16 + l15) * 32
                                          + ((q4 ^ swz) * 8)];
        #pragma unroll
        for (int mi = 0; mi < 4; ++mi)
            #pragma unroll
            for (int ni = 0; ni < 4; ++ni)
                acc[mi][ni] = __builtin_amdgcn_mfma_f32_16x16x32_bf16(
                    af[mi], bfr[ni], acc[mi][ni], 0, 0, 0);
        __syncthreads();
    }
    #pragma unroll
    for (int mi = 0; mi < 4; ++mi) {
        #pragma unroll
        for (int ni = 0; ni < 4; ++ni) {
            int col = col0 + wn * 64 + ni * 16 + l15;
            float bb = bias[col];
            #pragma unroll
            for (int j = 0; j < 4; ++j) {
                int row = row0 + wm * 64 + mi * 16 + q4 * 4 + j;
                if (row < M)
                    C[(size_t)row * N + col] = acc[mi][ni][j] + bb;
            }
        }
    }
}

// ---------------------------------------------------------------------------
// K2: per-(b,c) softmax stats over 785 tokens of k (vectorized, r7 proven).
// ---------------------------------------------------------------------------
__global__ __launch_bounds__(256)
void softmax_stats_kernel(const ushort_t* __restrict__ k,
                          float* __restrict__ stat_m, float* __restrict__ stat_is) {
    const int b  = blockIdx.y;
    const int c0 = blockIdx.x * 64;
    const int tid = threadIdx.x;
    const int c8 = tid & 7, tg = tid >> 3;   // chunk 0..7, token-group 0..31
    __shared__ float red[32][64];
    __shared__ float smB[64];
    const ushort_t* base = k + (size_t)b * NTOK * DIM + c0 + c8 * 8;

    float mx[8];
    #pragma unroll
    for (int j = 0; j < 8; ++j) mx[j] = -1e30f;
    for (int n = tg; n < NTOK; n += 32) {
        union { s16x8 v; ushort_t u[8]; } kv;
        kv.v = *(const s16x8*)(base + (size_t)n * DIM);
        #pragma unroll
        for (int j = 0; j < 8; ++j) mx[j] = fmaxf(mx[j], bf2f(kv.u[j]));
    }
    #pragma unroll
    for (int j = 0; j < 8; ++j) red[tg][c8 * 8 + j] = mx[j];
    __syncthreads();
    if (tid < 64) {
        float M = red[0][tid];
        #pragma unroll
        for (int i = 1; i < 32; ++i) M = fmaxf(M, red[i][tid]);
        smB[tid] = M;
    }
    __syncthreads();

    float sm8[8], ss[8];
    #pragma unroll
    for (int j = 0; j < 8; ++j) { sm8[j] = smB[c8 * 8 + j]; ss[j] = 0.f; }
    for (int n = tg; n < NTOK; n += 32) {
        union { s16x8 v; ushort_t u[8]; } kv;
        kv.v = *(const s16x8*)(base + (size_t)n * DIM);
        #pragma unroll
        for (int j = 0; j < 8; ++j) ss[j] += __expf(bf2f(kv.u[j]) - sm8[j]);
    }
    __syncthreads();
    #pragma unroll
    for (int j = 0; j < 8; ++j) red[tg][c8 * 8 + j] = ss[j];
    __syncthreads();
    if (tid < 64) {
        float S = 0.f;
        #pragma unroll
        for (int i = 0; i < 32; ++i) S += red[i][tid];
        stat_m[b * DIM + c0 + tid]  = smB[tid];
        stat_is[b * DIM + c0 + tid] = 1.f / S;
    }
}

// ---------------------------------------------------------------------------
// K3: attn_part[ns][b,h,d,e] = sum_{n in chunk} exp(k[n,d]-m_d) * v[n,e]
// MFMA version (r6, verified). C = Ek^T * V, operands staged transposed f32,
// cvt8 on fragment read. 4 waves = 2x2 quadrants of 48x48.
// ---------------------------------------------------------------------------
__global__ __launch_bounds__(256)
void attn_kernel(const bf16* __restrict__ k, const bf16* __restrict__ v,
                 const float* __restrict__ stat_m,
                 float* __restrict__ attn_part) {
    const int h = blockIdx.x, b = blockIdx.y, ns = blockIdx.z;
    const int t = threadIdx.x;
    const int wave = t >> 6, lane = t & 63;
    const int q4 = lane >> 4, l15 = lane & 15;
    const int wd = wave >> 1, we = wave & 1;   // quadrant: d-half, e-half
    __shared__ float ekT[96][36];
    __shared__ float vT[96][36];
    __shared__ float smM[96];
    if (t < 96) smM[t] = stat_m[b * DIM + h * HD + t];
    __syncthreads();

    f32x4 acc[3][3];
    #pragma unroll
    for (int i = 0; i < 3; ++i)
        #pragma unroll
        for (int j = 0; j < 3; ++j) acc[i][j] = (f32x4){0.f, 0.f, 0.f, 0.f};

    const bf16* kbase = k + (size_t)b * NTOK * DIM + h * HD;
    const bf16* vbase = v + (size_t)b * NTOK * DIM + h * HD;
    const int nlo = ns * NPC;
    const int nhi = min(NTOK, nlo + NPC);
    const int tl = t >> 3;          // token slot 0..31
    const int cg = (t & 7) * 12;    // channel base 0,12,..,84
    for (int n0 = nlo; n0 < nhi; n0 += 32) {
        const int n = n0 + tl;
        if (n < nhi) {
            #pragma unroll
            for (int j = 0; j < 6; ++j) {
                float2 kf = __bfloat1622float2(
                    *(const __hip_bfloat162*)&kbase[(size_t)n * DIM + cg + 2 * j]);
                float2 vf = __bfloat1622float2(
                    *(const __hip_bfloat162*)&vbase[(size_t)n * DIM + cg + 2 * j]);
                ekT[cg + 2 * j][tl]     = __expf(kf.x - smM[cg + 2 * j]);
                ekT[cg + 2 * j + 1][tl] = __expf(kf.y - smM[cg + 2 * j + 1]);
                vT[cg + 2 * j][tl]      = vf.x;
                vT[cg + 2 * j + 1][tl]  = vf.y;
            }
        } else {
            #pragma unroll
            for (int j = 0; j < 12; ++j) {
                ekT[cg + j][tl] = 0.f;
                vT[cg + j][tl]  = 0.f;
            }
        }
        __syncthreads();
        s16x8 af[3], bfr[3];
        #pragma unroll
        for (int i = 0; i < 3; ++i)
            af[i] = cvt8(&ekT[wd * 48 + i * 16 + l15][q4 * 8]);
        #pragma unroll
        for (int i = 0; i < 3; ++i)
            bfr[i] = cvt8(&vT[we * 48 + i * 16 + l15][q4 * 8]);
        #pragma unroll
        for (int i = 0; i < 3; ++i)
            #pragma unroll
            for (int j = 0; j < 3; ++j)
                acc[i][j] = __builtin_amdgcn_mfma_f32_16x16x32_bf16(
                    af[i], bfr[j], acc[i][j], 0, 0, 0);
        __syncthreads();
    }
    float* abase = attn_part + (size_t)ns * BN * NH * HD * HD
                 + (size_t)(b * NH + h) * HD * HD;
    #pragma unroll
    for (int i = 0; i < 3; ++i)
        #pragma unroll
        for (int j = 0; j < 3; ++j)
            #pragma unroll
            for (int r = 0; r < 4; ++r)
                abase[(size_t)(wd * 48 + i * 16 + q4 * 4 + r) * HD
                      + we * 48 + j * 16 + l15] = acc[i][j][r];
}

// ---------------------------------------------------------------------------
// K3b: attn[b,h,d,e] = stat_is[b,h*96+d] * sum_s attn_part[s][b,h,d,e]
// ---------------------------------------------------------------------------
__global__ __launch_bounds__(256)
void attn_reduce_kernel(const float* __restrict__ part,
                        const float* __restrict__ stat_is,
                        float* __restrict__ attn) {
    const int TOT4 = BN * NH * HD * HD / 4;   // 589824
    int i = blockIdx.x * 256 + threadIdx.x;
    if (i >= TOT4) return;
    size_t base = (size_t)i * 4;
    int bh = (int)(base / (HD * HD));
    int d  = (int)((base / HD) % HD);
    float is = stat_is[(bh >> 3) * DIM + (bh & 7) * HD + d];
    const size_t PSZ = (size_t)BN * NH * HD * HD;
    float4 s = *(const float4*)&part[base];
    float4 p1 = *(const float4*)&part[PSZ + base];
    float4 p2 = *(const float4*)&part[2 * PSZ + base];
    float4 p3 = *(const float4*)&part[3 * PSZ + base];
    s.x = (s.x + p1.x + p2.x + p3.x) * is;
    s.y = (s.y + p1.y + p2.y + p3.y) * is;
    s.z = (s.z + p1.z + p2.z + p3.z) * is;
    s.w = (s.w + p1.w + p2.w + p3.w) * is;
    *(float4*)&attn[base] = s;
}

// ---------------------------------------------------------------------------
// K4: CRPE depthwise conv, restructured for occupancy + branch-free taps.
// ---------------------------------------------------------------------------
#define CRS 1104   // conv tile row stride in bf16 elems (34*32 + 16 pad)

template<int KS>
__device__ __forceinline__ void crpe_conv32(const ushort_t* __restrict__ vimg,
                                            const float* __restrict__ wsm,
                                            float b0, float b1,
                                            ushort_t* __restrict__ ob,
                                            int p, int yl, int y) {
    constexpr int R = KS / 2;
    const float* wA = wsm + (2 * p) * KS * KS;
    const float* wB = wA + KS * KS;
    #pragma unroll
    for (int xo = 0; xo < 28; xo += 7) {
        float a0[7], a1[7];
        #pragma unroll
        for (int u = 0; u < 7; ++u) { a0[u] = b0; a1[u] = b1; }
        #pragma unroll
        for (int ky = 0; ky < KS; ++ky) {
            const ushort_t* rp = vimg + (yl + ky - R + 3) * CRS
                                      + (xo - R + 3) * 32 + 2 * p;
            float2 seg[6 + KS];
            #pragma unroll
            for (int i = 0; i < 6 + KS; ++i)
                seg[i] = __bfloat1622float2(*(const __hip_bfloat162*)(rp + i * 32));
            #pragma unroll
            for (int kx = 0; kx < KS; ++kx) {
                float wa = wA[ky * KS + kx];
                float wb = wB[ky * KS + kx];
                #pragma unroll
                for (int u = 0; u < 7; ++u) {
                    a0[u] = fmaf(wa, seg[u + kx].x, a0[u]);
                    a1[u] = fmaf(wb, seg[u + kx].y, a1[u]);
                }
            }
        }
        #pragma unroll
        for (int u = 0; u < 7; ++u)
            *(__hip_bfloat162*)&ob[(size_t)(1 + y * GW + xo + u) * DIM + 2 * p] =
                __float22bfloat162_rn(make_float2(a0[u], a1[u]));
    }
}

__global__ __launch_bounds__(256)
void crpe_lds_kernel(const ushort_t* __restrict__ v,
                     const float* __restrict__ w3, const float* __restrict__ b3,
                     const float* __restrict__ w5, const float* __restrict__ b5,
                     const float* __restrict__ w7, const float* __restrict__ b7,
                     ushort_t* __restrict__ o) {
    __shared__ ushort_t vimg[20 * CRS];   // 44,160 B
    __shared__ float    wsm[32 * 49];     //  6,272 B
    const int cg  = blockIdx.x;    // 0..23, 32-channel group
    const int hf  = blockIdx.y;    // 0..1 image half (rows 0..13 / 14..27)
    const int b   = blockIdx.z;
    const int tid = threadIdx.x;
    const int c0  = cg * 32;

    const float* wsrc; const float* bsrc; int ks;
    if (c0 < 192)      { wsrc = w3 + c0 * 9;          bsrc = b3 + c0;         ks = 3; }
    else if (c0 < 480) { wsrc = w5 + (c0 - 192) * 25; bsrc = b5 + (c0 - 192); ks = 5; }
    else               { wsrc = w7 + (c0 - 480) * 49; bsrc = b7 + (c0 - 480); ks = 7; }
    const int ksq = ks * ks;

    const int zr0 = hf ? 17 : 0;
    for (int idx = tid; idx < 3 * 138; idx += 256) {
        int rr = idx / 138, cc = idx - rr * 138;
        *(s16x8*)&vimg[(zr0 + rr) * CRS + cc * 8] = (s16x8){0,0,0,0,0,0,0,0};
    }
    for (int idx = tid; idx < 17 * 24; idx += 256) {
        int vr = idx / 24, cc = idx - vr * 24;
        int ly = hf ? vr : vr + 3;
        int ch = (cc < 12) ? cc : (112 + cc);
        *(s16x8*)&vimg[ly * CRS + ch * 8] = (s16x8){0,0,0,0,0,0,0,0};
    }
    for (int idx = tid; idx < 32 * ksq; idx += 256)
        wsm[idx] = wsrc[idx];
    const ushort_t* vb = v + (size_t)b * NTOK * DIM + c0;
    const int gy0 = hf ? 11 : 0;
    for (int idx = tid; idx < 17 * 28 * 4; idx += 256) {
        int vr = idx / 112, rem = idx - vr * 112;
        int px = rem >> 2, c8 = rem & 3;
        int gy = gy0 + vr;
        int ly = hf ? vr : vr + 3;
        *(s16x8*)&vimg[ly * CRS + (px + 3) * 32 + c8 * 8] =
            *(const s16x8*)(vb + (size_t)(1 + gy * GW + px) * DIM + c8 * 8);
    }
    ushort_t* ob = o + (size_t)b * NTOK * DIM + c0;
    if (hf == 0 && tid < 32) ob[tid] = 0;   // CLS row: rp = 0
    __syncthreads();

    const int p  = tid & 15;       // channel pair 0..15
    const int yl = tid >> 4;       // row within half 0..15
    if (yl >= 14) return;
    const int y = hf * 14 + yl;    // global row
    float bb0 = bsrc[2 * p], bb1 = bsrc[2 * p + 1];
    if (ks == 3)      crpe_conv32<3>(vimg, wsm, bb0, bb1, ob, p, yl, y);
    else if (ks == 5) crpe_conv32<5>(vimg, wsm, bb0, bb1, ob, p, yl, y);
    else              crpe_conv32<7>(vimg, wsm, bb0, bb1, ob, p, yl, y);
}

// ---------------------------------------------------------------------------
// K5: o[b,n,h*96+e] = scale * sum_d q[n,d] attn[d,e] + q[n,e] * rp (in-place)
// MFMA version (r6, verified).
// ---------------------------------------------------------------------------
__global__ __launch_bounds__(256)
void combine_kernel(const ushort_t* __restrict__ q, const float* __restrict__ attn,
                    ushort_t* __restrict__ o) {
    const int h = blockIdx.x, b = blockIdx.z;
    const int n0 = blockIdx.y * 64;
    const int t = threadIdx.x;
    const int wave = t >> 6, lane = t & 63;
    const int q4 = lane >> 4, l15 = lane & 15;
    __shared__ ushort_t qs[64][104];
    __shared__ ushort_t atT[96][104];

    const ushort_t* qbase = q + (size_t)b * NTOK * DIM + h * HD;
    #pragma unroll
    for (int i = 0; i < 3; ++i) {
        int idx = t + i * 256;          // 0..767 = 64 rows x 12 chunks
        int rr = idx / 12, c8 = idx % 12;
        int n = n0 + rr;
        s16x8 val = (s16x8){0,0,0,0,0,0,0,0};
        if (n < NTOK) val = *(const s16x8*)(qbase + (size_t)n * DIM + c8 * 8);
        *(s16x8*)&qs[rr][c8 * 8] = val;
    }
    const float* abase = attn + (size_t)(b * NH + h) * HD * HD;
    #pragma unroll
    for (int i = 0; i < 36; ++i) {
        int idx = t + i * 256;          // 0..9215; read coalesced [d][e]
        int d = idx / 96, e = idx % 96;
        atT[e][d] = f2bf(abase[idx]);
    }
    __syncthreads();

    f32x4 acc[6];
    #pragma unroll
    for (int i = 0; i < 6; ++i) acc[i] = (f32x4){0.f, 0.f, 0.f, 0.f};
    #pragma unroll
    for (int ks = 0; ks < 3; ++ks) {
        s16x8 aq = *(const s16x8*)&qs[wave * 16 + l15][ks * 32 + q4 * 8];
        #pragma unroll
        for (int et = 0; et < 6; ++et) {
            s16x8 bfrg = *(const s16x8*)&atT[et * 16 + l15][ks * 32 + q4 * 8];
            acc[et] = __builtin_amdgcn_mfma_f32_16x16x32_bf16(
                aq, bfrg, acc[et], 0, 0, 0);
        }
    }

    const float scale = 0.10206207261596575f;  // 96^-0.5
    ushort_t* obase = o + (size_t)b * NTOK * DIM + h * HD;
    #pragma unroll
    for (int et = 0; et < 6; ++et) {
        int e = et * 16 + l15;
        #pragma unroll
        for (int r = 0; r < 4; ++r) {
            int rr = wave * 16 + q4 * 4 + r;
            int n = n0 + rr;
            if (n >= NTOK) continue;
            size_t oa = (size_t)n * DIM + e;
            float rp = __bfloat162float(*(const bf16*)&obase[oa]);
            float qv = __bfloat162float(*(const bf16*)&qs[rr][e]);
            obase[oa] = f2bf(scale * acc[et][r] + qv * rp);
        }
    }
}

// ---------------------------------------------------------------------------
extern "C" void kernel_launch(void* const* d_in, const int* in_sizes, int n_in,
                              void* d_out, int out_size, void* d_ws, size_t ws_size,
                              hipStream_t stream) {
    const float* x     = (const float*)d_in[0];
    const float* W_qkv = (const float*)d_in[1];
    const float* b_qkv = (const float*)d_in[2];
    const float* W_out = (const float*)d_in[3];
    const float* b_out = (const float*)d_in[4];
    const float* w3    = (const float*)d_in[5];
    const float* cb3   = (const float*)d_in[6];
    const float* w5    = (const float*)d_in[7];
    const float* cb5   = (const float*)d_in[8];
    const float* w7    = (const float*)d_in[9];
    const float* cb7   = (const float*)d_in[10];
    float* out = (float*)d_out;

    ushort_t* q = (ushort_t*)d_ws;
    ushort_t* k = q + (size_t)MROWS * DIM;
    ushort_t* v = k + (size_t)MROWS * DIM;
    float* attn    = (float*)(v + (size_t)MROWS * DIM);
    float* stat_m  = attn + (size_t)BN * NH * HD * HD;
    float* stat_is = stat_m + (size_t)BN * DIM;
    ushort_t* Wqkvt = (ushort_t*)(stat_is + (size_t)BN * DIM);
    ushort_t* Wot   = Wqkvt + (size_t)QKVD * DIM;
    ushort_t* o = k;   // alias: k dead after attn_kernel

    // d_out scratch layout: xb (bf16 x, 38.58 MB) then attn_part (37.75 MB).
    // Both dead before gemm_out_mfma writes d_out (77.17 MB total).
    ushort_t* xb = (ushort_t*)d_out;
    float* attn_part = (float*)d_out + (size_t)MROWS * DIM / 2;

    transpose_bf16_kernel<<<dim3(QKVD / 32, DIM / 32), dim3(32, 8), 0, stream>>>(
        W_qkv, Wqkvt, DIM, QKVD);
    transpose_bf16_kernel<<<dim3(DIM / 32, DIM / 32), dim3(32, 8), 0, stream>>>(
        W_out, Wot, DIM, DIM);
    {
        int n8 = MROWS * DIM / 8;
        f32_to_bf16_kernel<<<dim3((n8 + 255) / 256), 256, 0, stream>>>(x, xb, n8);
    }
    gemm_qkv_mfma<<<dim3(QKVD / 128, (MROWS + 127) / 128), 256, 0, stream>>>(
        xb, Wqkvt, b_qkv, q, k, v);
    softmax_stats_kernel<<<dim3(12, BN), 256, 0, stream>>>(
        k, stat_m, stat_is);
    attn_kernel<<<dim3(NH, BN, NS), 256, 0, stream>>>(
        (const bf16*)k, (const bf16*)v, stat_m, attn_part);
    {
        int tot4 = BN * NH * HD * HD / 4;
        attn_reduce_kernel<<<dim3((tot4 + 255) / 256), 256, 0, stream>>>(
            attn_part, stat_is, attn);
    }
    crpe_lds_kernel<<<dim3(24, 2, BN), 256, 0, stream>>>(
        v, w3, cb3, w5, cb5, w7, cb7, o);
    combine_kernel<<<dim3(NH, 13, BN), 256, 0, stream>>>(
        q, attn, o);
    gemm_out_mfma<<<dim3(DIM / 128, (MROWS + 127) / 128), 256, 0, stream>>>(
        o, Wot, b_out, out);
}